// Round 13
// baseline (394.061 us; speedup 1.0000x reference)
//
#include <hip/hip_runtime.h>
#include <hip/hip_bf16.h>
#include <math.h>

#define HID 128
#define PR 20     // rows per pool block (divides 10000/5000/2500)
#define CRPB 32   // conv rows per block
#define RCAP 6144 // radix candidate cap
#define MAXCELLS 4096

__device__ inline int wave_iscan(int v, int lane) {   // inclusive scan within 64-lane wave
#pragma unroll
  for (int off = 1; off < 64; off <<= 1) {
    int o = __shfl_up(v, off, 64);
    if (lane >= off) v += o;
  }
  return v;
}

// concentrated-histogram add: one atomic per (wave, distinct bin)
__device__ inline void agg_hist_add(unsigned* hist, unsigned bin, bool active, int lane) {
  unsigned long long rem = __ballot(active);
  while (rem) {
    int leader = (int)(__ffsll((long long)rem) - 1);
    unsigned lbin = (unsigned)__shfl((int)bin, leader, 64);
    unsigned long long match = __ballot(active && (bin == lbin));
    if (lane == leader) atomicAdd(&hist[lbin], (unsigned)__popcll(match));
    rem &= ~match;
  }
}

// ---------- fused mean-gather + GraphConv + score-scalar epilogue ----------
template <int K>
__global__ __launch_bounds__(128) void k_conv_fused(
    const float* __restrict__ x, const int* __restrict__ src, int n, float invk,
    const float* __restrict__ Wrel, const float* __restrict__ Wroot,
    const float* __restrict__ brel,
    const float* __restrict__ wprel, const float* __restrict__ wproot,
    float* __restrict__ out, float* __restrict__ uo, float* __restrict__ vo) {
  __shared__ float4 sagg4[CRPB][HID / 4];
  __shared__ float4 sx4[CRPB][HID / 4];
  __shared__ int ssrc[CRPB * K];
  int t = threadIdx.x;
  int i0 = blockIdx.x * CRPB;
  const int nK = n * K;
  for (int s = t; s < CRPB * K; s += 128) {
    int gi = i0 * K + s;
    int v = (gi < nK) ? src[gi] : 0;
    ssrc[s] = ((unsigned)v < (unsigned)n) ? v : 0;
  }
  __syncthreads();
  {
    int fq = t & 31, h = t >> 5;
    const float4* x4 = (const float4*)x;
    for (int r = h; r < CRPB; r += 4) {
      int row = i0 + r;
      float4 s = make_float4(0.f, 0.f, 0.f, 0.f);
      float4 xv = make_float4(0.f, 0.f, 0.f, 0.f);
      if (row < n) {
#pragma unroll
        for (int j = 0; j < K; ++j) {
          float4 xx = x4[(size_t)ssrc[r * K + j] * 32 + fq];
          s.x += xx.x; s.y += xx.y; s.z += xx.z; s.w += xx.w;
        }
        xv = x4[(size_t)row * 32 + fq];
      }
      s.x *= invk; s.y *= invk; s.z *= invk; s.w *= invk;
      sagg4[r][fq] = s;
      sx4[r][fq] = xv;
    }
  }
  __syncthreads();
  int q = t & 31, rg = t >> 5;
  const float4* Wrel4  = (const float4*)Wrel;
  const float4* Wroot4 = (const float4*)Wroot;
  float4 bq = ((const float4*)brel)[q];
  float4 acc[8];
#pragma unroll
  for (int rr = 0; rr < 8; ++rr) acc[rr] = bq;
  int rbase = rg * 8;
#pragma unroll 2
  for (int cq = 0; cq < HID / 4; ++cq) {
    float4 w1[4], w2[4];
#pragma unroll
    for (int uu = 0; uu < 4; ++uu) {
      w1[uu] = Wrel4[(cq * 4 + uu) * 32 + q];
      w2[uu] = Wroot4[(cq * 4 + uu) * 32 + q];
    }
#pragma unroll
    for (int rr = 0; rr < 8; ++rr) {
      float4 a  = sagg4[rbase + rr][cq];
      float4 xx = sx4[rbase + rr][cq];
      acc[rr].x += a.x*w1[0].x + a.y*w1[1].x + a.z*w1[2].x + a.w*w1[3].x
                 + xx.x*w2[0].x + xx.y*w2[1].x + xx.z*w2[2].x + xx.w*w2[3].x;
      acc[rr].y += a.x*w1[0].y + a.y*w1[1].y + a.z*w1[2].y + a.w*w1[3].y
                 + xx.x*w2[0].y + xx.y*w2[1].y + xx.z*w2[2].y + xx.w*w2[3].y;
      acc[rr].z += a.x*w1[0].z + a.y*w1[1].z + a.z*w1[2].z + a.w*w1[3].z
                 + xx.x*w2[0].z + xx.y*w2[1].z + xx.z*w2[2].z + xx.w*w2[3].z;
      acc[rr].w += a.x*w1[0].w + a.y*w1[1].w + a.z*w1[2].w + a.w*w1[3].w
                 + xx.x*w2[0].w + xx.y*w2[1].w + xx.z*w2[2].w + xx.w*w2[3].w;
    }
  }
  float4 wplq = ((const float4*)wprel)[q];
  float4 wprq = ((const float4*)wproot)[q];
#pragma unroll
  for (int rr = 0; rr < 8; ++rr) {
    int row = i0 + rbase + rr;
    float4 v = acc[rr];
    v.x = v.x > 0.f ? v.x : 0.f;
    v.y = v.y > 0.f ? v.y : 0.f;
    v.z = v.z > 0.f ? v.z : 0.f;
    v.w = v.w > 0.f ? v.w : 0.f;
    float pu = 0.f, pv = 0.f;
    if (row < n) {
      ((float4*)out)[(size_t)row * 32 + q] = v;
      pu = v.x * wplq.x + v.y * wplq.y + v.z * wplq.z + v.w * wplq.w;
      pv = v.x * wprq.x + v.y * wprq.y + v.z * wprq.z + v.w * wprq.w;
    }
#pragma unroll
    for (int o = 16; o; o >>= 1) {
      pu += __shfl_down(pu, o, 32);
      pv += __shfl_down(pv, o, 32);
    }
    if (q == 0 && row < n) { uo[row] = pu; vo[row] = pv; }
  }
}

// ---------- scalar score ----------
template <int K>
__global__ void k_score_lite(const float* __restrict__ u, const float* __restrict__ v,
                             const int* __restrict__ src, const float* __restrict__ bprel,
                             int n, float* __restrict__ score, unsigned* __restrict__ key) {
  int i = blockIdx.x * blockDim.x + threadIdx.x;
  if (i >= n) return;
  float s = v[i] + bprel[0];
#pragma unroll
  for (int j = 0; j < K; ++j) s += u[src[i * K + j]];
  float sc = tanhf(s);
  score[i] = sc;
  unsigned bb = __float_as_uint(sc);
  key[i] = (bb & 0x80000000u) ? ~bb : (bb | 0x80000000u);
}

// ---------- mega-select: aggregated atomics (no same-address RMW storms) ----------
__global__ __launch_bounds__(1024) void k_select(
    const unsigned* __restrict__ key, int n, int kk,
    const float* __restrict__ pos_in, int* __restrict__ perm,
    int* __restrict__ startsg, int* __restrict__ countsg,
    float2* __restrict__ spos, int* __restrict__ sidx,
    int cells, int Gg, float inv_w) {
  __shared__ unsigned hist[1024];
  __shared__ unsigned cand[RCAP];
  __shared__ unsigned hist256[256];
  __shared__ int lcnt[MAXCELLS];
  __shared__ int lcur[MAXCELLS];
  __shared__ unsigned sh_B, sh_above, sh_cnt, sh_remain, sh_prefix;
  __shared__ int wtA[16], wtB[16];
  int t = threadIdx.x;
  int lane = t & 63, wid = t >> 6;
  unsigned long long lmask = (1ull << lane) - 1ull;

  // ---- P1: 1024-bin histogram (top 10 bits), wave-aggregated atomics ----
  hist[t] = 0u;
  if (t == 0) sh_cnt = 0u;
  __syncthreads();
  for (int i = t; i < n; i += 1024) {
    unsigned kv = key[i];
    agg_hist_add(hist, kv >> 22, true, lane);
  }
  __syncthreads();
  // ---- P2: boundary-bin pick via shuffle scan ----
  {
    unsigned hv = hist[t];
    int iv = wave_iscan((int)hv, lane);
    if (lane == 63) wtA[wid] = iv;
    __syncthreads();
    int b = 0, tot = 0;
#pragma unroll
    for (int w2 = 0; w2 < 16; ++w2) { int s = wtA[w2]; if (w2 < wid) b += s; tot += s; }
    unsigned val = (unsigned)(iv + b);
    unsigned above_strict = (unsigned)tot - val;
    unsigned above_incl = above_strict + hv;
    if (above_incl >= (unsigned)kk && above_strict < (unsigned)kk) {
      sh_B = (unsigned)t;
      sh_above = above_strict;
    }
    __syncthreads();
  }
  unsigned B = sh_B, above = sh_above;
  int remain = kk - (int)above;
  // ---- P3: collect bin-B candidates via ballot compaction (1 atomic/wave/iter) ----
  for (int i = t; i < n; i += 1024) {
    unsigned kv = key[i];
    bool m = ((kv >> 22) == B);
    unsigned long long mm = __ballot(m);
    if (mm) {
      int leader = (int)(__ffsll((long long)mm) - 1);
      unsigned base = 0;
      if (lane == leader) base = atomicAdd(&sh_cnt, (unsigned)__popcll(mm));
      base = (unsigned)__shfl((int)base, leader, 64);
      if (m) {
        unsigned p = base + (unsigned)__popcll(mm & lmask);
        if (p < RCAP) cand[p] = kv;
      }
    }
  }
  __syncthreads();
  int cnt = (int)sh_cnt; if (cnt > RCAP) cnt = RCAP;
  if (t == 0) { sh_prefix = 0u; sh_remain = (unsigned)remain; }
  __syncthreads();
  // ---- P3b: 4-pass byte refine, aggregated hist + shuffle-scan pick ----
  for (int pass = 0; pass < 4; ++pass) {
    int shift = 24 - pass * 8;
    unsigned prefix = sh_prefix;
    unsigned rem = sh_remain;
    if (t < 256) hist256[t] = 0u;
    __syncthreads();
    unsigned himask = (pass == 0) ? 0u : (0xFFFFFFFFu << (shift + 8));
    for (int i = t; i < cnt; i += 1024) {
      unsigned kky = cand[i];
      bool act = ((kky & himask) == prefix);
      agg_hist_add(hist256, (kky >> shift) & 255u, act, lane);
    }
    __syncthreads();
    int hv = (t < 256) ? (int)hist256[t] : 0;
    int iv = wave_iscan(hv, lane);
    if (t < 256 && lane == 63) wtB[wid] = iv;   // wid 0..3
    __syncthreads();
    if (t < 256) {
      int b = 0, tot = 0;
#pragma unroll
      for (int w2 = 0; w2 < 4; ++w2) { int s = wtB[w2]; if (w2 < wid) b += s; tot += s; }
      unsigned val = (unsigned)(iv + b);
      unsigned sstrict = (unsigned)tot - val;
      if (sstrict < rem && sstrict + (unsigned)hv >= rem) {
        sh_prefix = prefix | ((unsigned)t << shift);
        sh_remain = rem - sstrict;
      }
    }
    __syncthreads();
  }
  unsigned T = sh_prefix;
  int Gt = (int)(above + (unsigned)remain - sh_remain);   // #{key > T}
  int need = kk - Gt;
  // ---- P4: strided-count compaction (deterministic thread-strided order) ----
  {
    int cg = 0, ce = 0;
    for (int i = t; i < n; i += 1024) {
      unsigned kv = key[i];
      cg += (kv > T);
      ce += (kv == T);
    }
    int ig = wave_iscan(cg, lane);
    int ie = wave_iscan(ce, lane);
    if (lane == 63) { wtA[wid] = ig; wtB[wid] = ie; }
    __syncthreads();
    int bg = 0, be = 0;
#pragma unroll
    for (int w2 = 0; w2 < 16; ++w2) { if (w2 < wid) { bg += wtA[w2]; be += wtB[w2]; } }
    int og = bg + ig - cg;                // exclusive prefix
    int oe = be + ie - ce;
    for (int i = t; i < n; i += 1024) {
      unsigned kv = key[i];
      if (kv > T) {
        perm[og++] = i;
      } else if (kv == T) {
        if (oe < need) perm[Gt + oe] = i;
        ++oe;
      }
    }
  }
  __syncthreads();
  // ---- P5-7: grid build for KNN (skip on last layer) ----
  if (cells > 0) {
    for (int c = t; c < cells; c += 1024) lcnt[c] = 0;
    __syncthreads();
    for (int j = t; j < kk; j += 1024) {
      int node = perm[j];
      float px = pos_in[node * 2], py = pos_in[node * 2 + 1];
      int cx = min(Gg - 1, max(0, (int)(px * inv_w)));
      int cy = min(Gg - 1, max(0, (int)(py * inv_w)));
      atomicAdd(&lcnt[cy * Gg + cx], 1);
    }
    __syncthreads();
    {
      int c0[4]; int base4 = t * 4; int s = 0;
#pragma unroll
      for (int u = 0; u < 4; ++u) {
        int idx = base4 + u;
        c0[u] = (idx < cells) ? lcnt[idx] : 0;
        s += c0[u];
      }
      int is = wave_iscan(s, lane);
      if (lane == 63) wtA[wid] = is;
      __syncthreads();
      int b = 0;
#pragma unroll
      for (int w2 = 0; w2 < 16; ++w2) { if (w2 < wid) b += wtA[w2]; }
      int excl = b + is - s;
#pragma unroll
      for (int u = 0; u < 4; ++u) {
        int idx = base4 + u;
        if (idx < cells) { startsg[idx] = excl; lcur[idx] = excl; countsg[idx] = c0[u]; excl += c0[u]; }
      }
    }
    __syncthreads();
    for (int j = t; j < kk; j += 1024) {
      int node = perm[j];
      float px = pos_in[node * 2], py = pos_in[node * 2 + 1];
      int cx = min(Gg - 1, max(0, (int)(px * inv_w)));
      int cy = min(Gg - 1, max(0, (int)(py * inv_w)));
      int pp = atomicAdd(&lcur[cy * Gg + cx], 1);
      spos[pp] = make_float2(px, py);
      sidx[pp] = j;
    }
  }
}

// ---------- pooled gather + per-block column-max ----------
template <int R>
__global__ __launch_bounds__(256) void k_pool_pmax(
    const float* __restrict__ x, const float* __restrict__ score,
    const int* __restrict__ perm, const float* __restrict__ pos_in,
    float* __restrict__ xout, float* __restrict__ pos_out, int store,
    float* __restrict__ pmax) {
  __shared__ float sm[2][HID];
  int f = threadIdx.x & 127;
  int half = threadIdx.x >> 7;
  int j0 = blockIdx.x * R;
  float mx = -1e30f;
  for (int r = half; r < R; r += 2) {
    int j = j0 + r;
    int node = perm[j];
    float v = score[node];
    float val = x[(size_t)node * HID + f] * v;
    if (store) {
      xout[(size_t)j * HID + f] = val;
      if (f < 2) pos_out[j * 2 + f] = pos_in[node * 2 + f];
    }
    mx = fmaxf(mx, val);
  }
  sm[half][f] = mx;
  __syncthreads();
  if (half == 0) pmax[blockIdx.x * HID + f] = fmaxf(sm[0][f], sm[1][f]);
}

// ---------- exact KNN, one wave per query ----------
template <int K>
__global__ __launch_bounds__(256) void k_knn_wave(const float2* __restrict__ spos,
                           const int* __restrict__ sidx,
                           const int* __restrict__ starts, const int* __restrict__ counts,
                           int m, int G, float w, float inv_w, int* __restrict__ src_out) {
  int lane = threadIdx.x & 63;
  int j = blockIdx.x * (blockDim.x >> 6) + (threadIdx.x >> 6);
  if (j >= m) return;
  float2 qp = spos[j];
  int q = sidx[j];
  int cx = min(G - 1, max(0, (int)(qp.x * inv_w)));
  int cy = min(G - 1, max(0, (int)(qp.y * inv_w)));

  float bd[K]; int bi[K];
#pragma unroll
  for (int t = 0; t < K; ++t) { bd[t] = 1e30f; bi[t] = 0; }

  auto scan_span = [&](int s, int e) {
    for (int p = s + lane; p < e; p += 64) {
      if (p == j) continue;
      float2 pp = spos[p];
      float dx = qp.x - pp.x, dy = qp.y - pp.y;
      float d = dx * dx + dy * dy;
      if (d < bd[K - 1]) {
        float dd = d; int ii = sidx[p];
#pragma unroll
        for (int t = 0; t < K; ++t) {
          bool sw = dd < bd[t];
          float od = bd[t]; int oi = bi[t];
          if (sw) { bd[t] = dd; bi[t] = ii; dd = od; ii = oi; }
        }
      }
    }
  };

  {
    int xl = max(0, cx - 1), xh = min(G - 1, cx + 1);
    int y0 = max(0, cy - 1), y1 = min(G - 1, cy + 1);
    int ss[3], ee[3]; int nr = 0;
    for (int y = y0; y <= y1; ++y) {
      int b = y * G;
      ss[nr] = starts[b + xl];
      ee[nr] = starts[b + xh] + counts[b + xh];
      ++nr;
    }
    for (int t = 0; t < nr; ++t) scan_span(ss[t], ee[t]);
  }

  int r = 1;
  unsigned long long mg[K];
  while (true) {
    unsigned long long tmp[K];
#pragma unroll
    for (int t = 0; t < K; ++t)
      tmp[t] = ((unsigned long long)__float_as_uint(bd[t]) << 32) | (unsigned)bi[t];
#pragma unroll
    for (int t = 0; t < K; ++t) {
      unsigned long long mn = tmp[0];
#pragma unroll
      for (int o = 1; o < 64; o <<= 1) {
        unsigned long long ot = __shfl_xor(mn, o, 64);
        if (ot < mn) mn = ot;
      }
      mg[t] = mn;
      if (tmp[0] == mn) {
#pragma unroll
        for (int s2 = 0; s2 < K - 1; ++s2) tmp[s2] = tmp[s2 + 1];
        tmp[K - 1] = ~0ull;
      }
    }
    float kth = __uint_as_float((unsigned)(mg[K - 1] >> 32));
    float bnd = 1e30f;
    if (cx - r > 0)     bnd = fminf(bnd, qp.x - (float)(cx - r) * w);
    if (cx + r < G - 1) bnd = fminf(bnd, (float)(cx + r + 1) * w - qp.x);
    if (cy - r > 0)     bnd = fminf(bnd, qp.y - (float)(cy - r) * w);
    if (cy + r < G - 1) bnd = fminf(bnd, (float)(cy + r + 1) * w - qp.y);
    if (bnd > 1e29f) break;
    float bb = fmaxf(bnd, 0.f) * 0.999f;
    if (kth < bb * bb) break;
    ++r;
    int xl = max(0, cx - r), xh = min(G - 1, cx + r);
    int yt = cy - r, yb = cy + r;
    if (yt >= 0)     { int b = yt * G; scan_span(starts[b + xl], starts[b + xh] + counts[b + xh]); }
    if (yb <= G - 1) { int b = yb * G; scan_span(starts[b + xl], starts[b + xh] + counts[b + xh]); }
    int ylo = max(0, cy - r + 1), yhi = min(G - 1, cy + r - 1);
    for (int y = ylo; y <= yhi; ++y) {
      int b = y * G;
      if (cx - r >= 0)     { int c = b + cx - r; scan_span(starts[c], starts[c] + counts[c]); }
      if (cx + r <= G - 1) { int c = b + cx + r; scan_span(starts[c], starts[c] + counts[c]); }
    }
  }
  if (lane == 0) {
#pragma unroll
    for (int t = 0; t < K; ++t) src_out[q * K + t] = (int)(unsigned)(mg[t] & 0xffffffffu);
  }
}

// ---------- final: reduce pmax segments -> xs, then MLP head ----------
__global__ __launch_bounds__(1024) void k_final(const float* __restrict__ pmax,
                        int P0, int P1, int P2,
                        const float* __restrict__ W1, const float* __restrict__ b1,
                        const float* __restrict__ W2, const float* __restrict__ b2,
                        float* __restrict__ out) {
  __shared__ float red[8][HID];
  __shared__ float sxs[3 * HID];
  __shared__ float h1[HID];
  int f = threadIdx.x & 127, ch = threadIdx.x >> 7;
  int off0 = 0, off1 = P0, off2 = P0 + P1, off3 = P0 + P1 + P2;
  int lo[3] = {off0, off1, off2};
  int hi[3] = {off1, off2, off3};
  for (int l = 0; l < 3; ++l) {
    float mx = -1e30f;
    for (int p = lo[l] + ch; p < hi[l]; p += 8) mx = fmaxf(mx, pmax[p * HID + f]);
    red[ch][f] = mx;
    __syncthreads();
    if (ch == 0) {
      float m2 = red[0][f];
#pragma unroll
      for (int u = 1; u < 8; ++u) m2 = fmaxf(m2, red[u][f]);
      sxs[l * HID + f] = m2;
    }
    __syncthreads();
  }
  if (threadIdx.x < HID) {
    float acc = b1[f];
    for (int c = 0; c < 3 * HID; ++c) acc += sxs[c] * W1[c * HID + f];
    h1[f] = acc > 0.f ? acc : 0.f;
  }
  __syncthreads();
  if (threadIdx.x < 5) {
    float a = b2[threadIdx.x];
    for (int c = 0; c < HID; ++c) a += h1[c] * W2[c * 5 + threadIdx.x];
    out[threadIdx.x] = a;
  }
}

extern "C" void kernel_launch(void* const* d_in, const int* in_sizes, int n_in,
                              void* d_out, int out_size, void* d_ws, size_t ws_size,
                              hipStream_t stream) {
  const float* x_in   = (const float*)d_in[0];
  const float* pos_in = (const float*)d_in[1];
  const int*   ei     = (const int*)d_in[2];
  const float* Wrel   = (const float*)d_in[3];
  const float* brel   = (const float*)d_in[4];
  const float* Wroot  = (const float*)d_in[5];
  const float* Wprel  = (const float*)d_in[6];
  const float* bprel  = (const float*)d_in[7];
  const float* Wproot = (const float*)d_in[8];
  const float* W1     = (const float*)d_in[9];
  const float* b1     = (const float*)d_in[10];
  const float* W2     = (const float*)d_in[11];
  const float* b2     = (const float*)d_in[12];
  float* out = (float*)d_out;

  const int N0 = in_sizes[0] / HID;   // 20000
  const int P0 = (N0 / 2) / PR, P1 = (N0 / 4) / PR, P2 = (N0 / 8) / PR;

  char* w = (char*)d_ws;
  float*    xB     = (float*)w;    w += (size_t)N0 * HID * 4;
  float*    xA     = (float*)w;    w += (size_t)(N0 / 2) * HID * 4;
  float*    score  = (float*)w;    w += (size_t)N0 * 4;
  unsigned* key    = (unsigned*)w; w += (size_t)N0 * 4;
  float*    ubuf   = (float*)w;    w += (size_t)N0 * 4;
  float*    vbuf   = (float*)w;    w += (size_t)N0 * 4;
  float*    posA   = (float*)w;    w += (size_t)(N0 / 2) * 2 * 4;
  float*    posB   = (float*)w;    w += (size_t)(N0 / 2) * 2 * 4;
  int*      srcbuf = (int*)w;      w += (size_t)(N0 / 2) * 8 * 4;
  int*      permb  = (int*)w;      w += (size_t)(N0 / 2) * 4;
  float*    pmax   = (float*)w;    w += (size_t)(P0 + P1 + P2) * HID * 4;
  int*      counts = (int*)w;      w += MAXCELLS * 4;
  int*      starts = (int*)w;      w += MAXCELLS * 4;
  float2*   spos   = (float2*)w;   w += (size_t)(N0 / 2) * 8;
  int*      sidx   = (int*)w;      w += (size_t)(N0 / 2) * 4;
  (void)ws_size; (void)n_in; (void)out_size;

  int n = N0;
  const float* xcur   = x_in;
  const float* poscur = pos_in;
  const int*   srccur = ei;
  int kcur = 6;
  int Poff = 0;

  for (int l = 0; l < 3; ++l) {
    const int kk = n / 2;
    int Gg = (int)ceilf(sqrtf((float)kk / 2.5f));
    if (Gg > 64) Gg = 64;
    if (Gg < 1) Gg = 1;
    int cells = Gg * Gg;
    float cw = 100.f / (float)Gg;
    float inv_w = (float)Gg / 100.f;
    int cblocks = (n + CRPB - 1) / CRPB;

    if (kcur == 6) {
      k_conv_fused<6><<<cblocks, 128, 0, stream>>>(xcur, srccur, n, 1.f / 6.f,
          Wrel + l * HID * HID, Wroot + l * HID * HID, brel + l * HID,
          Wprel + l * HID, Wproot + l * HID, xB, ubuf, vbuf);
      k_score_lite<6><<<(n + 255) / 256, 256, 0, stream>>>(ubuf, vbuf, srccur, bprel + l,
                                                           n, score, key);
    } else {
      k_conv_fused<8><<<cblocks, 128, 0, stream>>>(xcur, srccur, n, 1.f / 8.f,
          Wrel + l * HID * HID, Wroot + l * HID * HID, brel + l * HID,
          Wprel + l * HID, Wproot + l * HID, xB, ubuf, vbuf);
      k_score_lite<8><<<(n + 255) / 256, 256, 0, stream>>>(ubuf, vbuf, srccur, bprel + l,
                                                           n, score, key);
    }
    k_select<<<1, 1024, 0, stream>>>(key, n, kk, poscur, permb, starts, counts,
                                     spos, sidx, (l < 2) ? cells : 0, Gg, inv_w);
    float* pos_out = (l == 0) ? posA : posB;
    int store = (l < 2) ? 1 : 0;
    k_pool_pmax<PR><<<kk / PR, 256, 0, stream>>>(xB, score, permb, poscur, xA, pos_out,
                                                 store, pmax + (size_t)Poff * HID);
    Poff += kk / PR;
    n = kk;
    if (l == 0)      { k_knn_wave<6><<<(n + 3) / 4, 256, 0, stream>>>(spos, sidx, starts, counts,
                                                                      n, Gg, cw, inv_w, srcbuf); kcur = 6; }
    else if (l == 1) { k_knn_wave<8><<<(n + 3) / 4, 256, 0, stream>>>(spos, sidx, starts, counts,
                                                                      n, Gg, cw, inv_w, srcbuf); kcur = 8; }
    xcur = xA; poscur = pos_out; srccur = srcbuf;
  }
  k_final<<<1, 1024, 0, stream>>>(pmax, P0, P1, P2, W1, b1, W2, b2, out);
}

// Round 14
// 306.803 us; speedup vs baseline: 1.2844x; 1.2844x over previous
//
#include <hip/hip_runtime.h>
#include <hip/hip_bf16.h>
#include <math.h>

#define HID 128
#define PR 20     // rows per pool block (divides 10000/5000/2500)
#define CRPB 32   // conv rows per block
#define MAXCELLS 4096
// dynamic-LDS word offsets for k_select (u32 words)
#define SKEY_CAP 20480
#define OFF_HIST   (SKEY_CAP)            // 1024
#define OFF_H256   (SKEY_CAP + 1024)     // 256
#define OFF_LCNT   (SKEY_CAP + 1280)     // 4096
#define OFF_LCUR   (SKEY_CAP + 5376)     // 4096
#define SEL_WORDS  (SKEY_CAP + 9472)
#define SEL_BYTES  (SEL_WORDS * 4)       // 119808 B ≈ 117 KB (< 160 KB/CU)

__device__ inline int wave_iscan(int v, int lane) {   // inclusive scan within 64-lane wave
#pragma unroll
  for (int off = 1; off < 64; off <<= 1) {
    int o = __shfl_up(v, off, 64);
    if (lane >= off) v += o;
  }
  return v;
}

// ---------- fused mean-gather + GraphConv + score-scalar epilogue ----------
template <int K>
__global__ __launch_bounds__(128) void k_conv_fused(
    const float* __restrict__ x, const int* __restrict__ src, int n, float invk,
    const float* __restrict__ Wrel, const float* __restrict__ Wroot,
    const float* __restrict__ brel,
    const float* __restrict__ wprel, const float* __restrict__ wproot,
    float* __restrict__ out, float* __restrict__ uo, float* __restrict__ vo) {
  __shared__ float4 sagg4[CRPB][HID / 4];
  __shared__ float4 sx4[CRPB][HID / 4];
  __shared__ int ssrc[CRPB * K];
  int t = threadIdx.x;
  int i0 = blockIdx.x * CRPB;
  const int nK = n * K;
  for (int s = t; s < CRPB * K; s += 128) {
    int gi = i0 * K + s;
    int v = (gi < nK) ? src[gi] : 0;
    ssrc[s] = ((unsigned)v < (unsigned)n) ? v : 0;
  }
  __syncthreads();
  {
    int fq = t & 31, h = t >> 5;
    const float4* x4 = (const float4*)x;
    for (int r = h; r < CRPB; r += 4) {
      int row = i0 + r;
      float4 s = make_float4(0.f, 0.f, 0.f, 0.f);
      float4 xv = make_float4(0.f, 0.f, 0.f, 0.f);
      if (row < n) {
#pragma unroll
        for (int j = 0; j < K; ++j) {
          float4 xx = x4[(size_t)ssrc[r * K + j] * 32 + fq];
          s.x += xx.x; s.y += xx.y; s.z += xx.z; s.w += xx.w;
        }
        xv = x4[(size_t)row * 32 + fq];
      }
      s.x *= invk; s.y *= invk; s.z *= invk; s.w *= invk;
      sagg4[r][fq] = s;
      sx4[r][fq] = xv;
    }
  }
  __syncthreads();
  int q = t & 31, rg = t >> 5;
  const float4* Wrel4  = (const float4*)Wrel;
  const float4* Wroot4 = (const float4*)Wroot;
  float4 bq = ((const float4*)brel)[q];
  float4 acc[8];
#pragma unroll
  for (int rr = 0; rr < 8; ++rr) acc[rr] = bq;
  int rbase = rg * 8;
#pragma unroll 2
  for (int cq = 0; cq < HID / 4; ++cq) {
    float4 w1[4], w2[4];
#pragma unroll
    for (int uu = 0; uu < 4; ++uu) {
      w1[uu] = Wrel4[(cq * 4 + uu) * 32 + q];
      w2[uu] = Wroot4[(cq * 4 + uu) * 32 + q];
    }
#pragma unroll
    for (int rr = 0; rr < 8; ++rr) {
      float4 a  = sagg4[rbase + rr][cq];
      float4 xx = sx4[rbase + rr][cq];
      acc[rr].x += a.x*w1[0].x + a.y*w1[1].x + a.z*w1[2].x + a.w*w1[3].x
                 + xx.x*w2[0].x + xx.y*w2[1].x + xx.z*w2[2].x + xx.w*w2[3].x;
      acc[rr].y += a.x*w1[0].y + a.y*w1[1].y + a.z*w1[2].y + a.w*w1[3].y
                 + xx.x*w2[0].y + xx.y*w2[1].y + xx.z*w2[2].y + xx.w*w2[3].y;
      acc[rr].z += a.x*w1[0].z + a.y*w1[1].z + a.z*w1[2].z + a.w*w1[3].z
                 + xx.x*w2[0].z + xx.y*w2[1].z + xx.z*w2[2].z + xx.w*w2[3].z;
      acc[rr].w += a.x*w1[0].w + a.y*w1[1].w + a.z*w1[2].w + a.w*w1[3].w
                 + xx.x*w2[0].w + xx.y*w2[1].w + xx.z*w2[2].w + xx.w*w2[3].w;
    }
  }
  float4 wplq = ((const float4*)wprel)[q];
  float4 wprq = ((const float4*)wproot)[q];
#pragma unroll
  for (int rr = 0; rr < 8; ++rr) {
    int row = i0 + rbase + rr;
    float4 v = acc[rr];
    v.x = v.x > 0.f ? v.x : 0.f;
    v.y = v.y > 0.f ? v.y : 0.f;
    v.z = v.z > 0.f ? v.z : 0.f;
    v.w = v.w > 0.f ? v.w : 0.f;
    float pu = 0.f, pv = 0.f;
    if (row < n) {
      ((float4*)out)[(size_t)row * 32 + q] = v;
      pu = v.x * wplq.x + v.y * wplq.y + v.z * wplq.z + v.w * wplq.w;
      pv = v.x * wprq.x + v.y * wprq.y + v.z * wprq.z + v.w * wprq.w;
    }
#pragma unroll
    for (int o = 16; o; o >>= 1) {
      pu += __shfl_down(pu, o, 32);
      pv += __shfl_down(pv, o, 32);
    }
    if (q == 0 && row < n) { uo[row] = pu; vo[row] = pv; }
  }
}

// ---------- scalar score ----------
template <int K>
__global__ void k_score_lite(const float* __restrict__ u, const float* __restrict__ v,
                             const int* __restrict__ src, const float* __restrict__ bprel,
                             int n, float* __restrict__ score, unsigned* __restrict__ key) {
  int i = blockIdx.x * blockDim.x + threadIdx.x;
  if (i >= n) return;
  float s = v[i] + bprel[0];
#pragma unroll
  for (int j = 0; j < K; ++j) s += u[src[i * K + j]];
  float sc = tanhf(s);
  score[i] = sc;
  unsigned bb = __float_as_uint(sc);
  key[i] = (bb & 0x80000000u) ? ~bb : (bb | 0x80000000u);
}

// ---------- mega-select: ONE global scan, all phases on LDS-resident keys ----------
__global__ __launch_bounds__(1024) void k_select(
    const unsigned* __restrict__ key, int n, int kk,
    const float* __restrict__ pos_in, int* __restrict__ perm,
    int* __restrict__ startsg, int* __restrict__ countsg,
    float2* __restrict__ spos, int* __restrict__ sidx,
    int cells, int Gg, float inv_w) {
  extern __shared__ unsigned lds[];
  unsigned* skey    = lds;               // [SKEY_CAP]
  unsigned* hist    = lds + OFF_HIST;    // [1024]
  unsigned* hist256 = lds + OFF_H256;    // [256]
  int*      lcnt    = (int*)(lds + OFF_LCNT); // [4096]
  int*      lcur    = (int*)(lds + OFF_LCUR); // [4096]
  __shared__ unsigned sh_B, sh_above, sh_remain, sh_prefix;
  __shared__ int wtA[16], wtB[16];
  int t = threadIdx.x;
  int lane = t & 63, wid = t >> 6;

  // ---- P0+P1: load keys to LDS (uint4) + build 1024-bin histogram in one pass ----
  hist[t] = 0u;
  __syncthreads();
  const uint4* key4 = (const uint4*)key;
  int n4 = n >> 2;                        // n divisible by 4
  for (int i = t; i < n4; i += 1024) {
    uint4 kv = key4[i];
    *(uint4*)&skey[i * 4] = kv;
    atomicAdd(&hist[kv.x >> 22], 1u);
    atomicAdd(&hist[kv.y >> 22], 1u);
    atomicAdd(&hist[kv.z >> 22], 1u);
    atomicAdd(&hist[kv.w >> 22], 1u);
  }
  __syncthreads();
  // ---- P2: boundary-bin pick via shuffle scan ----
  {
    unsigned hv = hist[t];
    int iv = wave_iscan((int)hv, lane);
    if (lane == 63) wtA[wid] = iv;
    __syncthreads();
    int b = 0, tot = 0;
#pragma unroll
    for (int w2 = 0; w2 < 16; ++w2) { int s = wtA[w2]; if (w2 < wid) b += s; tot += s; }
    unsigned val = (unsigned)(iv + b);
    unsigned above_strict = (unsigned)tot - val;
    unsigned above_incl = above_strict + hv;
    if (above_incl >= (unsigned)kk && above_strict < (unsigned)kk) {
      sh_B = (unsigned)t;
      sh_above = above_strict;
    }
    __syncthreads();
  }
  unsigned B = sh_B, above = sh_above;
  int remain = kk - (int)above;
  if (t == 0) { sh_prefix = 0u; sh_remain = (unsigned)remain; }
  __syncthreads();
  // ---- P3b: 4-pass byte refine directly on LDS keys (filter top10==B && prefix) ----
  for (int pass = 0; pass < 4; ++pass) {
    int shift = 24 - pass * 8;
    unsigned prefix = sh_prefix;
    unsigned rem = sh_remain;
    if (t < 256) hist256[t] = 0u;
    __syncthreads();
    unsigned himask = (pass == 0) ? 0u : (0xFFFFFFFFu << (shift + 8));
    for (int i = t; i < n; i += 1024) {
      unsigned kky = skey[i];
      if ((kky >> 22) == B && (kky & himask) == prefix)
        atomicAdd(&hist256[(kky >> shift) & 255u], 1u);
    }
    __syncthreads();
    int hv = (t < 256) ? (int)hist256[t] : 0;
    int iv = wave_iscan(hv, lane);
    if (t < 256 && lane == 63) wtB[wid] = iv;   // wid 0..3
    __syncthreads();
    if (t < 256) {
      int b = 0, tot = 0;
#pragma unroll
      for (int w2 = 0; w2 < 4; ++w2) { int s = wtB[w2]; if (w2 < wid) b += s; tot += s; }
      unsigned val = (unsigned)(iv + b);
      unsigned sstrict = (unsigned)tot - val;
      if (sstrict < rem && sstrict + (unsigned)hv >= rem) {
        sh_prefix = prefix | ((unsigned)t << shift);
        sh_remain = rem - sstrict;
      }
    }
    __syncthreads();
  }
  unsigned T = sh_prefix;
  int Gt = (int)(above + (unsigned)remain - sh_remain);   // #{key > T}
  int need = kk - Gt;
  // ---- P4: strided-count compaction over LDS keys (thread-strided order) ----
  {
    int cg = 0, ce = 0;
    for (int i = t; i < n; i += 1024) {
      unsigned kv = skey[i];
      cg += (kv > T);
      ce += (kv == T);
    }
    int ig = wave_iscan(cg, lane);
    int ie = wave_iscan(ce, lane);
    if (lane == 63) { wtA[wid] = ig; wtB[wid] = ie; }
    __syncthreads();
    int bg = 0, be = 0;
#pragma unroll
    for (int w2 = 0; w2 < 16; ++w2) { if (w2 < wid) { bg += wtA[w2]; be += wtB[w2]; } }
    int og = bg + ig - cg;                // exclusive prefix
    int oe = be + ie - ce;
    for (int i = t; i < n; i += 1024) {
      unsigned kv = skey[i];
      if (kv > T) {
        perm[og++] = i;
      } else if (kv == T) {
        if (oe < need) perm[Gt + oe] = i;
        ++oe;
      }
    }
  }
  __syncthreads();
  // ---- P5-7: grid build for KNN (skip on last layer) ----
  if (cells > 0) {
    for (int c = t; c < cells; c += 1024) lcnt[c] = 0;
    __syncthreads();
    for (int j = t; j < kk; j += 1024) {
      int node = perm[j];
      float px = pos_in[node * 2], py = pos_in[node * 2 + 1];
      int cx = min(Gg - 1, max(0, (int)(px * inv_w)));
      int cy = min(Gg - 1, max(0, (int)(py * inv_w)));
      atomicAdd(&lcnt[cy * Gg + cx], 1);
    }
    __syncthreads();
    {
      int c0[4]; int base4 = t * 4; int s = 0;
#pragma unroll
      for (int u = 0; u < 4; ++u) {
        int idx = base4 + u;
        c0[u] = (idx < cells) ? lcnt[idx] : 0;
        s += c0[u];
      }
      int is = wave_iscan(s, lane);
      if (lane == 63) wtA[wid] = is;
      __syncthreads();
      int b = 0;
#pragma unroll
      for (int w2 = 0; w2 < 16; ++w2) { if (w2 < wid) b += wtA[w2]; }
      int excl = b + is - s;
#pragma unroll
      for (int u = 0; u < 4; ++u) {
        int idx = base4 + u;
        if (idx < cells) { startsg[idx] = excl; lcur[idx] = excl; countsg[idx] = c0[u]; excl += c0[u]; }
      }
    }
    __syncthreads();
    for (int j = t; j < kk; j += 1024) {
      int node = perm[j];
      float px = pos_in[node * 2], py = pos_in[node * 2 + 1];
      int cx = min(Gg - 1, max(0, (int)(px * inv_w)));
      int cy = min(Gg - 1, max(0, (int)(py * inv_w)));
      int pp = atomicAdd(&lcur[cy * Gg + cx], 1);
      spos[pp] = make_float2(px, py);
      sidx[pp] = j;
    }
  }
}

// ---------- pooled gather + per-block column-max ----------
template <int R>
__global__ __launch_bounds__(256) void k_pool_pmax(
    const float* __restrict__ x, const float* __restrict__ score,
    const int* __restrict__ perm, const float* __restrict__ pos_in,
    float* __restrict__ xout, float* __restrict__ pos_out, int store,
    float* __restrict__ pmax) {
  __shared__ float sm[2][HID];
  int f = threadIdx.x & 127;
  int half = threadIdx.x >> 7;
  int j0 = blockIdx.x * R;
  float mx = -1e30f;
  for (int r = half; r < R; r += 2) {
    int j = j0 + r;
    int node = perm[j];
    float v = score[node];
    float val = x[(size_t)node * HID + f] * v;
    if (store) {
      xout[(size_t)j * HID + f] = val;
      if (f < 2) pos_out[j * 2 + f] = pos_in[node * 2 + f];
    }
    mx = fmaxf(mx, val);
  }
  sm[half][f] = mx;
  __syncthreads();
  if (half == 0) pmax[blockIdx.x * HID + f] = fmaxf(sm[0][f], sm[1][f]);
}

// ---------- exact KNN, one wave per query ----------
template <int K>
__global__ __launch_bounds__(256) void k_knn_wave(const float2* __restrict__ spos,
                           const int* __restrict__ sidx,
                           const int* __restrict__ starts, const int* __restrict__ counts,
                           int m, int G, float w, float inv_w, int* __restrict__ src_out) {
  int lane = threadIdx.x & 63;
  int j = blockIdx.x * (blockDim.x >> 6) + (threadIdx.x >> 6);
  if (j >= m) return;
  float2 qp = spos[j];
  int q = sidx[j];
  int cx = min(G - 1, max(0, (int)(qp.x * inv_w)));
  int cy = min(G - 1, max(0, (int)(qp.y * inv_w)));

  float bd[K]; int bi[K];
#pragma unroll
  for (int t = 0; t < K; ++t) { bd[t] = 1e30f; bi[t] = 0; }

  auto scan_span = [&](int s, int e) {
    for (int p = s + lane; p < e; p += 64) {
      if (p == j) continue;
      float2 pp = spos[p];
      float dx = qp.x - pp.x, dy = qp.y - pp.y;
      float d = dx * dx + dy * dy;
      if (d < bd[K - 1]) {
        float dd = d; int ii = sidx[p];
#pragma unroll
        for (int t = 0; t < K; ++t) {
          bool sw = dd < bd[t];
          float od = bd[t]; int oi = bi[t];
          if (sw) { bd[t] = dd; bi[t] = ii; dd = od; ii = oi; }
        }
      }
    }
  };

  {
    int xl = max(0, cx - 1), xh = min(G - 1, cx + 1);
    int y0 = max(0, cy - 1), y1 = min(G - 1, cy + 1);
    int ss[3], ee[3]; int nr = 0;
    for (int y = y0; y <= y1; ++y) {
      int b = y * G;
      ss[nr] = starts[b + xl];
      ee[nr] = starts[b + xh] + counts[b + xh];
      ++nr;
    }
    for (int t = 0; t < nr; ++t) scan_span(ss[t], ee[t]);
  }

  int r = 1;
  unsigned long long mg[K];
  while (true) {
    unsigned long long tmp[K];
#pragma unroll
    for (int t = 0; t < K; ++t)
      tmp[t] = ((unsigned long long)__float_as_uint(bd[t]) << 32) | (unsigned)bi[t];
#pragma unroll
    for (int t = 0; t < K; ++t) {
      unsigned long long mn = tmp[0];
#pragma unroll
      for (int o = 1; o < 64; o <<= 1) {
        unsigned long long ot = __shfl_xor(mn, o, 64);
        if (ot < mn) mn = ot;
      }
      mg[t] = mn;
      if (tmp[0] == mn) {
#pragma unroll
        for (int s2 = 0; s2 < K - 1; ++s2) tmp[s2] = tmp[s2 + 1];
        tmp[K - 1] = ~0ull;
      }
    }
    float kth = __uint_as_float((unsigned)(mg[K - 1] >> 32));
    float bnd = 1e30f;
    if (cx - r > 0)     bnd = fminf(bnd, qp.x - (float)(cx - r) * w);
    if (cx + r < G - 1) bnd = fminf(bnd, (float)(cx + r + 1) * w - qp.x);
    if (cy - r > 0)     bnd = fminf(bnd, qp.y - (float)(cy - r) * w);
    if (cy + r < G - 1) bnd = fminf(bnd, (float)(cy + r + 1) * w - qp.y);
    if (bnd > 1e29f) break;
    float bb = fmaxf(bnd, 0.f) * 0.999f;
    if (kth < bb * bb) break;
    ++r;
    int xl = max(0, cx - r), xh = min(G - 1, cx + r);
    int yt = cy - r, yb = cy + r;
    if (yt >= 0)     { int b = yt * G; scan_span(starts[b + xl], starts[b + xh] + counts[b + xh]); }
    if (yb <= G - 1) { int b = yb * G; scan_span(starts[b + xl], starts[b + xh] + counts[b + xh]); }
    int ylo = max(0, cy - r + 1), yhi = min(G - 1, cy + r - 1);
    for (int y = ylo; y <= yhi; ++y) {
      int b = y * G;
      if (cx - r >= 0)     { int c = b + cx - r; scan_span(starts[c], starts[c] + counts[c]); }
      if (cx + r <= G - 1) { int c = b + cx + r; scan_span(starts[c], starts[c] + counts[c]); }
    }
  }
  if (lane == 0) {
#pragma unroll
    for (int t = 0; t < K; ++t) src_out[q * K + t] = (int)(unsigned)(mg[t] & 0xffffffffu);
  }
}

// ---------- final: reduce pmax segments -> xs, then MLP head ----------
__global__ __launch_bounds__(1024) void k_final(const float* __restrict__ pmax,
                        int P0, int P1, int P2,
                        const float* __restrict__ W1, const float* __restrict__ b1,
                        const float* __restrict__ W2, const float* __restrict__ b2,
                        float* __restrict__ out) {
  __shared__ float red[8][HID];
  __shared__ float sxs[3 * HID];
  __shared__ float h1[HID];
  int f = threadIdx.x & 127, ch = threadIdx.x >> 7;
  int off0 = 0, off1 = P0, off2 = P0 + P1, off3 = P0 + P1 + P2;
  int lo[3] = {off0, off1, off2};
  int hi[3] = {off1, off2, off3};
  for (int l = 0; l < 3; ++l) {
    float mx = -1e30f;
    for (int p = lo[l] + ch; p < hi[l]; p += 8) mx = fmaxf(mx, pmax[p * HID + f]);
    red[ch][f] = mx;
    __syncthreads();
    if (ch == 0) {
      float m2 = red[0][f];
#pragma unroll
      for (int u = 1; u < 8; ++u) m2 = fmaxf(m2, red[u][f]);
      sxs[l * HID + f] = m2;
    }
    __syncthreads();
  }
  if (threadIdx.x < HID) {
    float acc = b1[f];
    for (int c = 0; c < 3 * HID; ++c) acc += sxs[c] * W1[c * HID + f];
    h1[f] = acc > 0.f ? acc : 0.f;
  }
  __syncthreads();
  if (threadIdx.x < 5) {
    float a = b2[threadIdx.x];
    for (int c = 0; c < HID; ++c) a += h1[c] * W2[c * 5 + threadIdx.x];
    out[threadIdx.x] = a;
  }
}

extern "C" void kernel_launch(void* const* d_in, const int* in_sizes, int n_in,
                              void* d_out, int out_size, void* d_ws, size_t ws_size,
                              hipStream_t stream) {
  const float* x_in   = (const float*)d_in[0];
  const float* pos_in = (const float*)d_in[1];
  const int*   ei     = (const int*)d_in[2];
  const float* Wrel   = (const float*)d_in[3];
  const float* brel   = (const float*)d_in[4];
  const float* Wroot  = (const float*)d_in[5];
  const float* Wprel  = (const float*)d_in[6];
  const float* bprel  = (const float*)d_in[7];
  const float* Wproot = (const float*)d_in[8];
  const float* W1     = (const float*)d_in[9];
  const float* b1     = (const float*)d_in[10];
  const float* W2     = (const float*)d_in[11];
  const float* b2     = (const float*)d_in[12];
  float* out = (float*)d_out;

  const int N0 = in_sizes[0] / HID;   // 20000
  const int P0 = (N0 / 2) / PR, P1 = (N0 / 4) / PR, P2 = (N0 / 8) / PR;

  char* w = (char*)d_ws;
  float*    xB     = (float*)w;    w += (size_t)N0 * HID * 4;
  float*    xA     = (float*)w;    w += (size_t)(N0 / 2) * HID * 4;
  float*    score  = (float*)w;    w += (size_t)N0 * 4;
  unsigned* key    = (unsigned*)w; w += (size_t)N0 * 4;
  float*    ubuf   = (float*)w;    w += (size_t)N0 * 4;
  float*    vbuf   = (float*)w;    w += (size_t)N0 * 4;
  float*    posA   = (float*)w;    w += (size_t)(N0 / 2) * 2 * 4;
  float*    posB   = (float*)w;    w += (size_t)(N0 / 2) * 2 * 4;
  int*      srcbuf = (int*)w;      w += (size_t)(N0 / 2) * 8 * 4;
  int*      permb  = (int*)w;      w += (size_t)(N0 / 2) * 4;
  float*    pmax   = (float*)w;    w += (size_t)(P0 + P1 + P2) * HID * 4;
  int*      counts = (int*)w;      w += MAXCELLS * 4;
  int*      starts = (int*)w;      w += MAXCELLS * 4;
  float2*   spos   = (float2*)w;   w += (size_t)(N0 / 2) * 8;
  int*      sidx   = (int*)w;      w += (size_t)(N0 / 2) * 4;
  (void)ws_size; (void)n_in; (void)out_size;

  int n = N0;
  const float* xcur   = x_in;
  const float* poscur = pos_in;
  const int*   srccur = ei;
  int kcur = 6;
  int Poff = 0;

  for (int l = 0; l < 3; ++l) {
    const int kk = n / 2;
    int Gg = (int)ceilf(sqrtf((float)kk / 2.5f));
    if (Gg > 64) Gg = 64;
    if (Gg < 1) Gg = 1;
    int cells = Gg * Gg;
    float cw = 100.f / (float)Gg;
    float inv_w = (float)Gg / 100.f;
    int cblocks = (n + CRPB - 1) / CRPB;

    if (kcur == 6) {
      k_conv_fused<6><<<cblocks, 128, 0, stream>>>(xcur, srccur, n, 1.f / 6.f,
          Wrel + l * HID * HID, Wroot + l * HID * HID, brel + l * HID,
          Wprel + l * HID, Wproot + l * HID, xB, ubuf, vbuf);
      k_score_lite<6><<<(n + 255) / 256, 256, 0, stream>>>(ubuf, vbuf, srccur, bprel + l,
                                                           n, score, key);
    } else {
      k_conv_fused<8><<<cblocks, 128, 0, stream>>>(xcur, srccur, n, 1.f / 8.f,
          Wrel + l * HID * HID, Wroot + l * HID * HID, brel + l * HID,
          Wprel + l * HID, Wproot + l * HID, xB, ubuf, vbuf);
      k_score_lite<8><<<(n + 255) / 256, 256, 0, stream>>>(ubuf, vbuf, srccur, bprel + l,
                                                           n, score, key);
    }
    k_select<<<1, 1024, SEL_BYTES, stream>>>(key, n, kk, poscur, permb, starts, counts,
                                             spos, sidx, (l < 2) ? cells : 0, Gg, inv_w);
    float* pos_out = (l == 0) ? posA : posB;
    int store = (l < 2) ? 1 : 0;
    k_pool_pmax<PR><<<kk / PR, 256, 0, stream>>>(xB, score, permb, poscur, xA, pos_out,
                                                 store, pmax + (size_t)Poff * HID);
    Poff += kk / PR;
    n = kk;
    if (l == 0)      { k_knn_wave<6><<<(n + 3) / 4, 256, 0, stream>>>(spos, sidx, starts, counts,
                                                                      n, Gg, cw, inv_w, srcbuf); kcur = 6; }
    else if (l == 1) { k_knn_wave<8><<<(n + 3) / 4, 256, 0, stream>>>(spos, sidx, starts, counts,
                                                                      n, Gg, cw, inv_w, srcbuf); kcur = 8; }
    xcur = xA; poscur = pos_out; srccur = srcbuf;
  }
  k_final<<<1, 1024, 0, stream>>>(pmax, P0, P1, P2, W1, b1, W2, b2, out);
}

// Round 15
// 281.108 us; speedup vs baseline: 1.4018x; 1.0914x over previous
//
#include <hip/hip_runtime.h>
#include <hip/hip_bf16.h>
#include <math.h>

#define HID 128
#define PR 20      // rows per pool block
#define CRPB 32    // conv rows per block
#define CAND_CAP 8192
#define MAXEQ 8192
#define MAXCELLS 4096

__device__ inline int wave_iscan(int v, int lane) {   // inclusive scan within 64-lane wave
#pragma unroll
  for (int off = 1; off < 64; off <<= 1) {
    int o = __shfl_up(v, off, 64);
    if (lane >= off) v += o;
  }
  return v;
}

// ---------- fused mean-gather + GraphConv + score-scalar epilogue ----------
// 256 threads (4 waves); thread owns 4 consecutive cols x 4 rows. LDS 33KB -> 4 blocks/CU.
template <int K>
__global__ __launch_bounds__(256) void k_conv_fused(
    const float* __restrict__ x, const int* __restrict__ src, int n, float invk,
    const float* __restrict__ Wrel, const float* __restrict__ Wroot,
    const float* __restrict__ brel,
    const float* __restrict__ wprel, const float* __restrict__ wproot,
    float* __restrict__ out, float* __restrict__ uo, float* __restrict__ vo) {
  __shared__ float4 sagg4[CRPB][HID / 4];
  __shared__ float4 sx4[CRPB][HID / 4];
  __shared__ int ssrc[CRPB * K];
  int t = threadIdx.x;
  int i0 = blockIdx.x * CRPB;
  const int nK = n * K;
  for (int s = t; s < CRPB * K; s += 256) {
    int gi = i0 * K + s;
    int v = (gi < nK) ? src[gi] : 0;
    ssrc[s] = ((unsigned)v < (unsigned)n) ? v : 0;
  }
  __syncthreads();
  {
    int fq = t & 31, h = t >> 5;            // col quad, row slot (8 slots x 4 rows)
    const float4* x4 = (const float4*)x;
    for (int r = h; r < CRPB; r += 8) {
      int row = i0 + r;
      float4 s = make_float4(0.f, 0.f, 0.f, 0.f);
      float4 xv = make_float4(0.f, 0.f, 0.f, 0.f);
      if (row < n) {
#pragma unroll
        for (int j = 0; j < K; ++j) {
          float4 xx = x4[(size_t)ssrc[r * K + j] * 32 + fq];
          s.x += xx.x; s.y += xx.y; s.z += xx.z; s.w += xx.w;
        }
        xv = x4[(size_t)row * 32 + fq];
      }
      s.x *= invk; s.y *= invk; s.z *= invk; s.w *= invk;
      sagg4[r][fq] = s;
      sx4[r][fq] = xv;
    }
  }
  __syncthreads();
  int q = t & 31, rg = t >> 5;              // col quad; row group (rows rg*4..rg*4+3)
  const float4* Wrel4  = (const float4*)Wrel;
  const float4* Wroot4 = (const float4*)Wroot;
  float4 bq = ((const float4*)brel)[q];
  float4 acc[4];
#pragma unroll
  for (int rr = 0; rr < 4; ++rr) acc[rr] = bq;
  int rbase = rg * 4;
#pragma unroll 2
  for (int cq = 0; cq < HID / 4; ++cq) {
    float4 w1[4], w2[4];
#pragma unroll
    for (int uu = 0; uu < 4; ++uu) {
      w1[uu] = Wrel4[(cq * 4 + uu) * 32 + q];
      w2[uu] = Wroot4[(cq * 4 + uu) * 32 + q];
    }
#pragma unroll
    for (int rr = 0; rr < 4; ++rr) {
      float4 a  = sagg4[rbase + rr][cq];
      float4 xx = sx4[rbase + rr][cq];
      acc[rr].x += a.x*w1[0].x + a.y*w1[1].x + a.z*w1[2].x + a.w*w1[3].x
                 + xx.x*w2[0].x + xx.y*w2[1].x + xx.z*w2[2].x + xx.w*w2[3].x;
      acc[rr].y += a.x*w1[0].y + a.y*w1[1].y + a.z*w1[2].y + a.w*w1[3].y
                 + xx.x*w2[0].y + xx.y*w2[1].y + xx.z*w2[2].y + xx.w*w2[3].y;
      acc[rr].z += a.x*w1[0].z + a.y*w1[1].z + a.z*w1[2].z + a.w*w1[3].z
                 + xx.x*w2[0].z + xx.y*w2[1].z + xx.z*w2[2].z + xx.w*w2[3].z;
      acc[rr].w += a.x*w1[0].w + a.y*w1[1].w + a.z*w1[2].w + a.w*w1[3].w
                 + xx.x*w2[0].w + xx.y*w2[1].w + xx.z*w2[2].w + xx.w*w2[3].w;
    }
  }
  float4 wplq = ((const float4*)wprel)[q];
  float4 wprq = ((const float4*)wproot)[q];
#pragma unroll
  for (int rr = 0; rr < 4; ++rr) {
    int row = i0 + rbase + rr;
    float4 v = acc[rr];
    v.x = v.x > 0.f ? v.x : 0.f;
    v.y = v.y > 0.f ? v.y : 0.f;
    v.z = v.z > 0.f ? v.z : 0.f;
    v.w = v.w > 0.f ? v.w : 0.f;
    float pu = 0.f, pv = 0.f;
    if (row < n) {
      ((float4*)out)[(size_t)row * 32 + q] = v;
      pu = v.x * wplq.x + v.y * wplq.y + v.z * wplq.z + v.w * wplq.w;
      pv = v.x * wprq.x + v.y * wprq.y + v.z * wprq.z + v.w * wprq.w;
    }
#pragma unroll
    for (int o = 16; o; o >>= 1) {
      pu += __shfl_down(pu, o, 32);
      pv += __shfl_down(pv, o, 32);
    }
    if (q == 0 && row < n) { uo[row] = pu; vo[row] = pv; }
  }
}

// ---------- scalar score ----------
template <int K>
__global__ void k_score_lite(const float* __restrict__ u, const float* __restrict__ v,
                             const int* __restrict__ src, const float* __restrict__ bprel,
                             int n, float* __restrict__ score, unsigned* __restrict__ key) {
  int i = blockIdx.x * blockDim.x + threadIdx.x;
  if (i >= n) return;
  float s = v[i] + bprel[0];
#pragma unroll
  for (int j = 0; j < K; ++j) s += u[src[i * K + j]];
  float sc = tanhf(s);
  score[i] = sc;
  unsigned bb = __float_as_uint(sc);
  key[i] = (bb & 0x80000000u) ? ~bb : (bb | 0x80000000u);
}

// ---------- grid-parallel 1024-bin histogram (per-block LDS, flush to global) ----------
__global__ __launch_bounds__(128) void k_hist(const unsigned* __restrict__ key, int n4,
                                              unsigned* __restrict__ ghist) {
  __shared__ unsigned lh[1024];
  int t = threadIdx.x;
#pragma unroll
  for (int u = 0; u < 8; ++u) lh[t + u * 128] = 0u;
  __syncthreads();
  int i = blockIdx.x * 128 + t;
  if (i < n4) {
    uint4 kv = ((const uint4*)key)[i];
    atomicAdd(&lh[kv.x >> 22], 1u);
    atomicAdd(&lh[kv.y >> 22], 1u);
    atomicAdd(&lh[kv.z >> 22], 1u);
    atomicAdd(&lh[kv.w >> 22], 1u);
  }
  __syncthreads();
#pragma unroll
  for (int u = 0; u < 8; ++u) {
    unsigned v = lh[t + u * 128];
    if (v) atomicAdd(&ghist[t + u * 128], v);
  }
}

// ---------- pick: boundary bin from ghist, collect candidates, 4-pass refine -> T, Gt ----------
__global__ __launch_bounds__(1024) void k_pick(const unsigned* __restrict__ key, int n, int kk,
                                               const unsigned* __restrict__ ghist,
                                               unsigned* __restrict__ outTG) {
  __shared__ unsigned cand[CAND_CAP];
  __shared__ unsigned hist256[256];
  __shared__ unsigned sh_B, sh_above, sh_cnt, sh_remain, sh_prefix;
  __shared__ int wtA[16], wtB[4];
  int t = threadIdx.x;
  int lane = t & 63, wid = t >> 6;
  unsigned long long lmask = (1ull << lane) - 1ull;
  if (t == 0) sh_cnt = 0u;
  // pick boundary bin B
  {
    unsigned hv = ghist[t];
    int iv = wave_iscan((int)hv, lane);
    if (lane == 63) wtA[wid] = iv;
    __syncthreads();
    int b = 0, tot = 0;
#pragma unroll
    for (int w2 = 0; w2 < 16; ++w2) { int s = wtA[w2]; if (w2 < wid) b += s; tot += s; }
    unsigned val = (unsigned)(iv + b);
    unsigned above_strict = (unsigned)tot - val;
    unsigned above_incl = above_strict + hv;
    if (above_incl >= (unsigned)kk && above_strict < (unsigned)kk) {
      sh_B = (unsigned)t;
      sh_above = above_strict;
    }
    __syncthreads();
  }
  unsigned B = sh_B, above = sh_above;
  int remain = kk - (int)above;
  // collect bin-B candidates (ballot-compacted; 1 LDS atomic per wave per iter)
  for (int i = t; i < n; i += 1024) {
    unsigned kv = key[i];
    bool m = ((kv >> 22) == B);
    unsigned long long mm = __ballot(m);
    if (mm) {
      int leader = (int)(__ffsll((long long)mm) - 1);
      unsigned base = 0;
      if (lane == leader) base = atomicAdd(&sh_cnt, (unsigned)__popcll(mm));
      base = (unsigned)__shfl((int)base, leader, 64);
      if (m) {
        unsigned p = base + (unsigned)__popcll(mm & lmask);
        if (p < CAND_CAP) cand[p] = kv;
      }
    }
  }
  __syncthreads();
  int cnt = (int)sh_cnt; if (cnt > CAND_CAP) cnt = CAND_CAP;
  if (t == 0) { sh_prefix = 0u; sh_remain = (unsigned)remain; }
  __syncthreads();
  // 4-pass byte refine (sub-bins are ~uniform -> no atomic concentration)
  for (int pass = 0; pass < 4; ++pass) {
    int shift = 24 - pass * 8;
    unsigned prefix = sh_prefix;
    unsigned rem = sh_remain;
    if (t < 256) hist256[t] = 0u;
    __syncthreads();
    unsigned himask = (pass == 0) ? 0u : (0xFFFFFFFFu << (shift + 8));
    for (int i = t; i < cnt; i += 1024) {
      unsigned kky = cand[i];
      if ((kky & himask) == prefix) atomicAdd(&hist256[(kky >> shift) & 255u], 1u);
    }
    __syncthreads();
    int hv = (t < 256) ? (int)hist256[t] : 0;
    int iv = wave_iscan(hv, lane);
    if (t < 256 && lane == 63) wtB[wid] = iv;
    __syncthreads();
    if (t < 256) {
      int b = 0, tot = 0;
#pragma unroll
      for (int w2 = 0; w2 < 4; ++w2) { int s = wtB[w2]; if (w2 < wid) b += s; tot += s; }
      unsigned val = (unsigned)(iv + b);
      unsigned sstrict = (unsigned)tot - val;
      if (sstrict < rem && sstrict + (unsigned)hv >= rem) {
        sh_prefix = prefix | ((unsigned)t << shift);
        sh_remain = rem - sstrict;
      }
    }
    __syncthreads();
  }
  if (t == 0) {
    outTG[0] = sh_prefix;
    outTG[1] = above + (unsigned)remain - sh_remain;   // Gt = #{key > T}
  }
}

// ---------- grid-parallel compaction (wave-aggregated global atomics) ----------
__global__ void k_sel(const unsigned* __restrict__ key, int n,
                      const unsigned* __restrict__ TG,
                      int* __restrict__ perm, int* __restrict__ cntGt,
                      int* __restrict__ eqbuf, int* __restrict__ cntEq) {
  int i = blockIdx.x * blockDim.x + threadIdx.x;
  int lane = threadIdx.x & 63;
  unsigned long long lmask = (1ull << lane) - 1ull;
  unsigned T = TG[0];
  unsigned kv = (i < n) ? key[i] : 0u;
  bool g = (i < n) && (kv > T);
  bool e = (i < n) && (kv == T);
  unsigned long long mg = __ballot(g);
  unsigned long long me = __ballot(e);
  if (mg) {
    int leader = (int)(__ffsll((long long)mg) - 1);
    int base = 0;
    if (lane == leader) base = atomicAdd(cntGt, (int)__popcll(mg));
    base = __shfl(base, leader, 64);
    if (g) perm[base + (int)__popcll(mg & lmask)] = i;
  }
  if (me) {
    int leader = (int)(__ffsll((long long)me) - 1);
    int base = 0;
    if (lane == leader) base = atomicAdd(cntEq, (int)__popcll(me));
    base = __shfl(base, leader, 64);
    if (e) {
      int p = base + (int)__popcll(me & lmask);
      if (p < MAXEQ) eqbuf[p] = i;
    }
  }
}

// ---------- boundary-equals: pick `need` lowest indices ----------
__global__ void k_sel_eq_fin(const unsigned* __restrict__ TG, const int* __restrict__ eqbuf,
                             const int* __restrict__ cntEq, int* __restrict__ perm, int kk) {
  int lane = threadIdx.x;        // 64
  int G = (int)TG[1];
  int need = kk - G;
  int cnt = *cntEq; if (cnt > MAXEQ) cnt = MAXEQ;
  int prev = -1;
  for (int t = 0; t < need; ++t) {
    int mymin = 0x7fffffff;
    for (int u = lane; u < cnt; u += 64) {
      int v = eqbuf[u];
      if (v > prev && v < mymin) mymin = v;
    }
    for (int o = 1; o < 64; o <<= 1) mymin = min(mymin, __shfl_xor(mymin, o, 64));
    if (lane == 0) perm[G + t] = mymin;
    prev = mymin;
  }
}

// ---------- pooled gather + per-block column-max + fused grid-cell count ----------
template <int R>
__global__ __launch_bounds__(256) void k_pool_pmax(
    const float* __restrict__ x, const float* __restrict__ score,
    const int* __restrict__ perm, const float* __restrict__ pos_in,
    float* __restrict__ xout, float* __restrict__ pos_out, int store,
    float* __restrict__ pmax, int* __restrict__ counts, int Gg, float inv_w) {
  __shared__ float sm[2][HID];
  int f = threadIdx.x & 127;
  int half = threadIdx.x >> 7;
  int j0 = blockIdx.x * R;
  float mx = -1e30f;
  for (int r = half; r < R; r += 2) {
    int j = j0 + r;
    int node = perm[j];
    float v = score[node];
    float val = x[(size_t)node * HID + f] * v;
    if (store) {
      xout[(size_t)j * HID + f] = val;
      if (f == 0) {
        float px = pos_in[node * 2], py = pos_in[node * 2 + 1];
        pos_out[j * 2] = px; pos_out[j * 2 + 1] = py;
        int cx = min(Gg - 1, max(0, (int)(px * inv_w)));
        int cy = min(Gg - 1, max(0, (int)(py * inv_w)));
        atomicAdd(&counts[cy * Gg + cx], 1);
      }
    }
    mx = fmaxf(mx, val);
  }
  sm[half][f] = mx;
  __syncthreads();
  if (half == 0) pmax[blockIdx.x * HID + f] = fmaxf(sm[0][f], sm[1][f]);
}

// ---------- grid scan (1 block over <=4096 cells) ----------
__global__ __launch_bounds__(1024) void k_grid_scan(const int* __restrict__ counts,
                                                    int* __restrict__ starts,
                                                    int* __restrict__ cursor, int cells) {
  __shared__ int wtA[16];
  int t = threadIdx.x;
  int lane = t & 63, wid = t >> 6;
  int c0[4]; int base4 = t * 4; int s = 0;
#pragma unroll
  for (int u = 0; u < 4; ++u) {
    int idx = base4 + u;
    c0[u] = (idx < cells) ? counts[idx] : 0;
    s += c0[u];
  }
  int is = wave_iscan(s, lane);
  if (lane == 63) wtA[wid] = is;
  __syncthreads();
  int b = 0;
#pragma unroll
  for (int w2 = 0; w2 < 16; ++w2) { if (w2 < wid) b += wtA[w2]; }
  int excl = b + is - s;
#pragma unroll
  for (int u = 0; u < 4; ++u) {
    int idx = base4 + u;
    if (idx < cells) { starts[idx] = excl; cursor[idx] = excl; excl += c0[u]; }
  }
}

__global__ void k_grid_scatter(const float2* __restrict__ pos, int m, int Gg, float inv_w,
                               int* __restrict__ cursor, float2* __restrict__ spos,
                               int* __restrict__ sidx) {
  int i = blockIdx.x * blockDim.x + threadIdx.x;
  if (i >= m) return;
  float2 p = pos[i];
  int cx = min(Gg - 1, max(0, (int)(p.x * inv_w)));
  int cy = min(Gg - 1, max(0, (int)(p.y * inv_w)));
  int pp = atomicAdd(&cursor[cy * Gg + cx], 1);
  spos[pp] = p;
  sidx[pp] = i;
}

// ---------- exact KNN, one wave per query ----------
template <int K>
__global__ __launch_bounds__(256) void k_knn_wave(const float2* __restrict__ spos,
                           const int* __restrict__ sidx,
                           const int* __restrict__ starts, const int* __restrict__ counts,
                           int m, int G, float w, float inv_w, int* __restrict__ src_out) {
  int lane = threadIdx.x & 63;
  int j = blockIdx.x * (blockDim.x >> 6) + (threadIdx.x >> 6);
  if (j >= m) return;
  float2 qp = spos[j];
  int q = sidx[j];
  int cx = min(G - 1, max(0, (int)(qp.x * inv_w)));
  int cy = min(G - 1, max(0, (int)(qp.y * inv_w)));

  float bd[K]; int bi[K];
#pragma unroll
  for (int t = 0; t < K; ++t) { bd[t] = 1e30f; bi[t] = 0; }

  auto scan_span = [&](int s, int e) {
    for (int p = s + lane; p < e; p += 64) {
      if (p == j) continue;
      float2 pp = spos[p];
      float dx = qp.x - pp.x, dy = qp.y - pp.y;
      float d = dx * dx + dy * dy;
      if (d < bd[K - 1]) {
        float dd = d; int ii = sidx[p];
#pragma unroll
        for (int t = 0; t < K; ++t) {
          bool sw = dd < bd[t];
          float od = bd[t]; int oi = bi[t];
          if (sw) { bd[t] = dd; bi[t] = ii; dd = od; ii = oi; }
        }
      }
    }
  };

  {
    int xl = max(0, cx - 1), xh = min(G - 1, cx + 1);
    int y0 = max(0, cy - 1), y1 = min(G - 1, cy + 1);
    int ss[3], ee[3]; int nr = 0;
    for (int y = y0; y <= y1; ++y) {
      int b = y * G;
      ss[nr] = starts[b + xl];
      ee[nr] = starts[b + xh] + counts[b + xh];
      ++nr;
    }
    for (int t = 0; t < nr; ++t) scan_span(ss[t], ee[t]);
  }

  int r = 1;
  unsigned long long mg[K];
  while (true) {
    unsigned long long tmp[K];
#pragma unroll
    for (int t = 0; t < K; ++t)
      tmp[t] = ((unsigned long long)__float_as_uint(bd[t]) << 32) | (unsigned)bi[t];
#pragma unroll
    for (int t = 0; t < K; ++t) {
      unsigned long long mn = tmp[0];
#pragma unroll
      for (int o = 1; o < 64; o <<= 1) {
        unsigned long long ot = __shfl_xor(mn, o, 64);
        if (ot < mn) mn = ot;
      }
      mg[t] = mn;
      if (tmp[0] == mn) {
#pragma unroll
        for (int s2 = 0; s2 < K - 1; ++s2) tmp[s2] = tmp[s2 + 1];
        tmp[K - 1] = ~0ull;
      }
    }
    float kth = __uint_as_float((unsigned)(mg[K - 1] >> 32));
    float bnd = 1e30f;
    if (cx - r > 0)     bnd = fminf(bnd, qp.x - (float)(cx - r) * w);
    if (cx + r < G - 1) bnd = fminf(bnd, (float)(cx + r + 1) * w - qp.x);
    if (cy - r > 0)     bnd = fminf(bnd, qp.y - (float)(cy - r) * w);
    if (cy + r < G - 1) bnd = fminf(bnd, (float)(cy + r + 1) * w - qp.y);
    if (bnd > 1e29f) break;
    float bb = fmaxf(bnd, 0.f) * 0.999f;
    if (kth < bb * bb) break;
    ++r;
    int xl = max(0, cx - r), xh = min(G - 1, cx + r);
    int yt = cy - r, yb = cy + r;
    if (yt >= 0)     { int b = yt * G; scan_span(starts[b + xl], starts[b + xh] + counts[b + xh]); }
    if (yb <= G - 1) { int b = yb * G; scan_span(starts[b + xl], starts[b + xh] + counts[b + xh]); }
    int ylo = max(0, cy - r + 1), yhi = min(G - 1, cy + r - 1);
    for (int y = ylo; y <= yhi; ++y) {
      int b = y * G;
      if (cx - r >= 0)     { int c = b + cx - r; scan_span(starts[c], starts[c] + counts[c]); }
      if (cx + r <= G - 1) { int c = b + cx + r; scan_span(starts[c], starts[c] + counts[c]); }
    }
  }
  if (lane == 0) {
#pragma unroll
    for (int t = 0; t < K; ++t) src_out[q * K + t] = (int)(unsigned)(mg[t] & 0xffffffffu);
  }
}

// ---------- final: reduce pmax segments -> xs, then MLP head ----------
__global__ __launch_bounds__(1024) void k_final(const float* __restrict__ pmax,
                        int P0, int P1, int P2,
                        const float* __restrict__ W1, const float* __restrict__ b1,
                        const float* __restrict__ W2, const float* __restrict__ b2,
                        float* __restrict__ out) {
  __shared__ float red[8][HID];
  __shared__ float sxs[3 * HID];
  __shared__ float h1[HID];
  int f = threadIdx.x & 127, ch = threadIdx.x >> 7;
  int off0 = 0, off1 = P0, off2 = P0 + P1, off3 = P0 + P1 + P2;
  int lo[3] = {off0, off1, off2};
  int hi[3] = {off1, off2, off3};
  for (int l = 0; l < 3; ++l) {
    float mx = -1e30f;
    for (int p = lo[l] + ch; p < hi[l]; p += 8) mx = fmaxf(mx, pmax[p * HID + f]);
    red[ch][f] = mx;
    __syncthreads();
    if (ch == 0) {
      float m2 = red[0][f];
#pragma unroll
      for (int u = 1; u < 8; ++u) m2 = fmaxf(m2, red[u][f]);
      sxs[l * HID + f] = m2;
    }
    __syncthreads();
  }
  if (threadIdx.x < HID) {
    float acc = b1[f];
    for (int c = 0; c < 3 * HID; ++c) acc += sxs[c] * W1[c * HID + f];
    h1[f] = acc > 0.f ? acc : 0.f;
  }
  __syncthreads();
  if (threadIdx.x < 5) {
    float a = b2[threadIdx.x];
    for (int c = 0; c < HID; ++c) a += h1[c] * W2[c * 5 + threadIdx.x];
    out[threadIdx.x] = a;
  }
}

extern "C" void kernel_launch(void* const* d_in, const int* in_sizes, int n_in,
                              void* d_out, int out_size, void* d_ws, size_t ws_size,
                              hipStream_t stream) {
  const float* x_in   = (const float*)d_in[0];
  const float* pos_in = (const float*)d_in[1];
  const int*   ei     = (const int*)d_in[2];
  const float* Wrel   = (const float*)d_in[3];
  const float* brel   = (const float*)d_in[4];
  const float* Wroot  = (const float*)d_in[5];
  const float* Wprel  = (const float*)d_in[6];
  const float* bprel  = (const float*)d_in[7];
  const float* Wproot = (const float*)d_in[8];
  const float* W1     = (const float*)d_in[9];
  const float* b1     = (const float*)d_in[10];
  const float* W2     = (const float*)d_in[11];
  const float* b2     = (const float*)d_in[12];
  float* out = (float*)d_out;

  const int N0 = in_sizes[0] / HID;   // 20000
  const int P0 = (N0 / 2) / PR, P1 = (N0 / 4) / PR, P2 = (N0 / 8) / PR;

  char* w = (char*)d_ws;
  float*    xB     = (float*)w;    w += (size_t)N0 * HID * 4;
  float*    xA     = (float*)w;    w += (size_t)(N0 / 2) * HID * 4;
  float*    score  = (float*)w;    w += (size_t)N0 * 4;
  unsigned* key    = (unsigned*)w; w += (size_t)N0 * 4;
  float*    ubuf   = (float*)w;    w += (size_t)N0 * 4;
  float*    vbuf   = (float*)w;    w += (size_t)N0 * 4;
  float*    posA   = (float*)w;    w += (size_t)(N0 / 2) * 2 * 4;
  float*    posB   = (float*)w;    w += (size_t)(N0 / 2) * 2 * 4;
  int*      srcbuf = (int*)w;      w += (size_t)(N0 / 2) * 8 * 4;
  int*      permb  = (int*)w;      w += (size_t)(N0 / 2) * 4;
  float*    pmax   = (float*)w;    w += (size_t)(P0 + P1 + P2) * HID * 4;
  // zeroed-together region: [ghist 4KB][cnt 32B][counts 16KB]
  unsigned* ghist  = (unsigned*)w; w += 1024 * 4;
  int*      cnt    = (int*)w;      w += 32;              // cntGt, cntEq
  int*      counts = (int*)w;      w += MAXCELLS * 4;
  const size_t ZERO_BYTES = 1024 * 4 + 32 + MAXCELLS * 4;
  unsigned* TG     = (unsigned*)w; w += 16;
  int*      eqbuf  = (int*)w;      w += MAXEQ * 4;
  int*      starts = (int*)w;      w += MAXCELLS * 4;
  int*      cursor = (int*)w;      w += MAXCELLS * 4;
  float2*   spos   = (float2*)w;   w += (size_t)(N0 / 2) * 8;
  int*      sidx   = (int*)w;      w += (size_t)(N0 / 2) * 4;
  (void)ws_size; (void)n_in; (void)out_size;

  int n = N0;
  const float* xcur   = x_in;
  const float* poscur = pos_in;
  const int*   srccur = ei;
  int kcur = 6;
  int Poff = 0;

  for (int l = 0; l < 3; ++l) {
    const int kk = n / 2;
    int Gg = (int)ceilf(sqrtf((float)kk / 2.5f));
    if (Gg > 64) Gg = 64;
    if (Gg < 1) Gg = 1;
    int cells = Gg * Gg;
    float cw = 100.f / (float)Gg;
    float inv_w = (float)Gg / 100.f;
    int cblocks = (n + CRPB - 1) / CRPB;

    hipMemsetAsync(ghist, 0, ZERO_BYTES, stream);   // ghist + cnt + counts

    if (kcur == 6) {
      k_conv_fused<6><<<cblocks, 256, 0, stream>>>(xcur, srccur, n, 1.f / 6.f,
          Wrel + l * HID * HID, Wroot + l * HID * HID, brel + l * HID,
          Wprel + l * HID, Wproot + l * HID, xB, ubuf, vbuf);
      k_score_lite<6><<<(n + 255) / 256, 256, 0, stream>>>(ubuf, vbuf, srccur, bprel + l,
                                                           n, score, key);
    } else {
      k_conv_fused<8><<<cblocks, 256, 0, stream>>>(xcur, srccur, n, 1.f / 8.f,
          Wrel + l * HID * HID, Wroot + l * HID * HID, brel + l * HID,
          Wprel + l * HID, Wproot + l * HID, xB, ubuf, vbuf);
      k_score_lite<8><<<(n + 255) / 256, 256, 0, stream>>>(ubuf, vbuf, srccur, bprel + l,
                                                           n, score, key);
    }
    int n4 = n >> 2;
    k_hist<<<(n4 + 127) / 128, 128, 0, stream>>>(key, n4, ghist);
    k_pick<<<1, 1024, 0, stream>>>(key, n, kk, ghist, TG);
    k_sel<<<(n + 255) / 256, 256, 0, stream>>>(key, n, TG, permb, cnt, eqbuf, cnt + 1);
    k_sel_eq_fin<<<1, 64, 0, stream>>>(TG, eqbuf, cnt + 1, permb, kk);

    float* pos_out = (l == 0) ? posA : posB;
    int store = (l < 2) ? 1 : 0;
    k_pool_pmax<PR><<<kk / PR, 256, 0, stream>>>(xB, score, permb, poscur, xA, pos_out,
                                                 store, pmax + (size_t)Poff * HID,
                                                 counts, Gg, inv_w);
    Poff += kk / PR;
    n = kk;
    if (l < 2) {
      k_grid_scan<<<1, 1024, 0, stream>>>(counts, starts, cursor, cells);
      k_grid_scatter<<<(n + 255) / 256, 256, 0, stream>>>((const float2*)pos_out, n, Gg, inv_w,
                                                          cursor, spos, sidx);
      if (l == 0) { k_knn_wave<6><<<(n + 3) / 4, 256, 0, stream>>>(spos, sidx, starts, counts,
                                                                   n, Gg, cw, inv_w, srcbuf); kcur = 6; }
      else        { k_knn_wave<8><<<(n + 3) / 4, 256, 0, stream>>>(spos, sidx, starts, counts,
                                                                   n, Gg, cw, inv_w, srcbuf); kcur = 8; }
    }
    xcur = xA; poscur = pos_out; srccur = srcbuf;
  }
  k_final<<<1, 1024, 0, stream>>>(pmax, P0, P1, P2, W1, b1, W2, b2, out);
}

// Round 16
// 266.351 us; speedup vs baseline: 1.4795x; 1.0554x over previous
//
#include <hip/hip_runtime.h>
#include <hip/hip_bf16.h>
#include <math.h>

#define HID 128
#define PR 20      // rows per pool block
#define CRPB 32    // conv rows per block
#define CAND_CAP 8192
#define MAXEQ 8192
#define MAXCELLS 4096

__device__ inline int wave_iscan(int v, int lane) {   // inclusive scan within 64-lane wave
#pragma unroll
  for (int off = 1; off < 64; off <<= 1) {
    int o = __shfl_up(v, off, 64);
    if (lane >= off) v += o;
  }
  return v;
}

// ---------- fused mean-gather + GraphConv + score-scalar epilogue ----------
template <int K>
__global__ __launch_bounds__(256) void k_conv_fused(
    const float* __restrict__ x, const int* __restrict__ src, int n, float invk,
    const float* __restrict__ Wrel, const float* __restrict__ Wroot,
    const float* __restrict__ brel,
    const float* __restrict__ wprel, const float* __restrict__ wproot,
    float* __restrict__ out, float* __restrict__ uo, float* __restrict__ vo) {
  __shared__ float4 sagg4[CRPB][HID / 4];
  __shared__ float4 sx4[CRPB][HID / 4];
  __shared__ int ssrc[CRPB * K];
  int t = threadIdx.x;
  int i0 = blockIdx.x * CRPB;
  const int nK = n * K;
  for (int s = t; s < CRPB * K; s += 256) {
    int gi = i0 * K + s;
    int v = (gi < nK) ? src[gi] : 0;
    ssrc[s] = ((unsigned)v < (unsigned)n) ? v : 0;
  }
  __syncthreads();
  {
    int fq = t & 31, h = t >> 5;
    const float4* x4 = (const float4*)x;
    for (int r = h; r < CRPB; r += 8) {
      int row = i0 + r;
      float4 s = make_float4(0.f, 0.f, 0.f, 0.f);
      float4 xv = make_float4(0.f, 0.f, 0.f, 0.f);
      if (row < n) {
#pragma unroll
        for (int j = 0; j < K; ++j) {
          float4 xx = x4[(size_t)ssrc[r * K + j] * 32 + fq];
          s.x += xx.x; s.y += xx.y; s.z += xx.z; s.w += xx.w;
        }
        xv = x4[(size_t)row * 32 + fq];
      }
      s.x *= invk; s.y *= invk; s.z *= invk; s.w *= invk;
      sagg4[r][fq] = s;
      sx4[r][fq] = xv;
    }
  }
  __syncthreads();
  int q = t & 31, rg = t >> 5;
  const float4* Wrel4  = (const float4*)Wrel;
  const float4* Wroot4 = (const float4*)Wroot;
  float4 bq = ((const float4*)brel)[q];
  float4 acc[4];
#pragma unroll
  for (int rr = 0; rr < 4; ++rr) acc[rr] = bq;
  int rbase = rg * 4;
#pragma unroll 2
  for (int cq = 0; cq < HID / 4; ++cq) {
    float4 w1[4], w2[4];
#pragma unroll
    for (int uu = 0; uu < 4; ++uu) {
      w1[uu] = Wrel4[(cq * 4 + uu) * 32 + q];
      w2[uu] = Wroot4[(cq * 4 + uu) * 32 + q];
    }
#pragma unroll
    for (int rr = 0; rr < 4; ++rr) {
      float4 a  = sagg4[rbase + rr][cq];
      float4 xx = sx4[rbase + rr][cq];
      acc[rr].x += a.x*w1[0].x + a.y*w1[1].x + a.z*w1[2].x + a.w*w1[3].x
                 + xx.x*w2[0].x + xx.y*w2[1].x + xx.z*w2[2].x + xx.w*w2[3].x;
      acc[rr].y += a.x*w1[0].y + a.y*w1[1].y + a.z*w1[2].y + a.w*w1[3].y
                 + xx.x*w2[0].y + xx.y*w2[1].y + xx.z*w2[2].y + xx.w*w2[3].y;
      acc[rr].z += a.x*w1[0].z + a.y*w1[1].z + a.z*w1[2].z + a.w*w1[3].z
                 + xx.x*w2[0].z + xx.y*w2[1].z + xx.z*w2[2].z + xx.w*w2[3].z;
      acc[rr].w += a.x*w1[0].w + a.y*w1[1].w + a.z*w1[2].w + a.w*w1[3].w
                 + xx.x*w2[0].w + xx.y*w2[1].w + xx.z*w2[2].w + xx.w*w2[3].w;
    }
  }
  float4 wplq = ((const float4*)wprel)[q];
  float4 wprq = ((const float4*)wproot)[q];
#pragma unroll
  for (int rr = 0; rr < 4; ++rr) {
    int row = i0 + rbase + rr;
    float4 v = acc[rr];
    v.x = v.x > 0.f ? v.x : 0.f;
    v.y = v.y > 0.f ? v.y : 0.f;
    v.z = v.z > 0.f ? v.z : 0.f;
    v.w = v.w > 0.f ? v.w : 0.f;
    float pu = 0.f, pv = 0.f;
    if (row < n) {
      ((float4*)out)[(size_t)row * 32 + q] = v;
      pu = v.x * wplq.x + v.y * wplq.y + v.z * wplq.z + v.w * wplq.w;
      pv = v.x * wprq.x + v.y * wprq.y + v.z * wprq.z + v.w * wprq.w;
    }
#pragma unroll
    for (int o = 16; o; o >>= 1) {
      pu += __shfl_down(pu, o, 32);
      pv += __shfl_down(pv, o, 32);
    }
    if (q == 0 && row < n) { uo[row] = pu; vo[row] = pv; }
  }
}

// ---------- scalar score ----------
template <int K>
__global__ void k_score_lite(const float* __restrict__ u, const float* __restrict__ v,
                             const int* __restrict__ src, const float* __restrict__ bprel,
                             int n, float* __restrict__ score, unsigned* __restrict__ key) {
  int i = blockIdx.x * blockDim.x + threadIdx.x;
  if (i >= n) return;
  float s = v[i] + bprel[0];
#pragma unroll
  for (int j = 0; j < K; ++j) s += u[src[i * K + j]];
  float sc = tanhf(s);
  score[i] = sc;
  unsigned bb = __float_as_uint(sc);
  key[i] = (bb & 0x80000000u) ? ~bb : (bb | 0x80000000u);
}

// ---------- grid-parallel 1024-bin histogram ----------
__global__ __launch_bounds__(128) void k_hist(const unsigned* __restrict__ key, int n4,
                                              unsigned* __restrict__ ghist) {
  __shared__ unsigned lh[1024];
  int t = threadIdx.x;
#pragma unroll
  for (int u = 0; u < 8; ++u) lh[t + u * 128] = 0u;
  __syncthreads();
  int i = blockIdx.x * 128 + t;
  if (i < n4) {
    uint4 kv = ((const uint4*)key)[i];
    atomicAdd(&lh[kv.x >> 22], 1u);
    atomicAdd(&lh[kv.y >> 22], 1u);
    atomicAdd(&lh[kv.z >> 22], 1u);
    atomicAdd(&lh[kv.w >> 22], 1u);
  }
  __syncthreads();
#pragma unroll
  for (int u = 0; u < 8; ++u) {
    unsigned v = lh[t + u * 128];
    if (v) atomicAdd(&ghist[t + u * 128], v);
  }
}

// ---------- pick boundary bin from ghist (1024 elems only) ----------
__global__ __launch_bounds__(1024) void k_pickbin(const unsigned* __restrict__ ghist, int kk,
                                                  unsigned* __restrict__ BA) {
  __shared__ int wtA[16];
  __shared__ unsigned sh_B, sh_above;
  int t = threadIdx.x;
  int lane = t & 63, wid = t >> 6;
  unsigned hv = ghist[t];
  int iv = wave_iscan((int)hv, lane);
  if (lane == 63) wtA[wid] = iv;
  __syncthreads();
  int b = 0, tot = 0;
#pragma unroll
  for (int w2 = 0; w2 < 16; ++w2) { int s = wtA[w2]; if (w2 < wid) b += s; tot += s; }
  unsigned val = (unsigned)(iv + b);
  unsigned above_strict = (unsigned)tot - val;
  unsigned above_incl = above_strict + hv;
  if (above_incl >= (unsigned)kk && above_strict < (unsigned)kk) {
    sh_B = (unsigned)t;
    sh_above = above_strict;
  }
  __syncthreads();
  if (t == 0) { BA[0] = sh_B; BA[1] = sh_above; }
}

// ---------- grid-parallel candidate collection (bin == B) ----------
__global__ void k_collect(const unsigned* __restrict__ key, int n,
                          const unsigned* __restrict__ BA,
                          unsigned* __restrict__ candbuf, int* __restrict__ candCnt) {
  int i = blockIdx.x * blockDim.x + threadIdx.x;
  int lane = threadIdx.x & 63;
  unsigned long long lmask = (1ull << lane) - 1ull;
  unsigned B = BA[0];
  unsigned kv = (i < n) ? key[i] : 0u;
  bool m = (i < n) && ((kv >> 22) == B);
  unsigned long long mm = __ballot(m);
  if (mm) {
    int leader = (int)(__ffsll((long long)mm) - 1);
    int base = 0;
    if (lane == leader) base = atomicAdd(candCnt, (int)__popcll(mm));
    base = __shfl(base, leader, 64);
    if (m) {
      int p = base + (int)__popcll(mm & lmask);
      if (p < CAND_CAP) candbuf[p] = kv;
    }
  }
}

// ---------- refine over candidates (LDS-staged, <=8K) -> T, Gt ----------
__global__ __launch_bounds__(1024) void k_refine(const unsigned* __restrict__ candbuf,
                                                 const int* __restrict__ candCnt,
                                                 const unsigned* __restrict__ BA, int kk,
                                                 unsigned* __restrict__ outTG) {
  __shared__ unsigned cand[CAND_CAP];
  __shared__ unsigned hist256[256];
  __shared__ unsigned sh_remain, sh_prefix;
  __shared__ int wtB[4];
  int t = threadIdx.x;
  int lane = t & 63, wid = t >> 6;
  unsigned B = BA[0], above = BA[1];
  int remain = kk - (int)above;
  int cnt = *candCnt; if (cnt > CAND_CAP) cnt = CAND_CAP;
  for (int i = t; i < cnt; i += 1024) cand[i] = candbuf[i];
  if (t == 0) { sh_prefix = 0u; sh_remain = (unsigned)remain; }
  __syncthreads();
  for (int pass = 0; pass < 4; ++pass) {
    int shift = 24 - pass * 8;
    unsigned prefix = sh_prefix;
    unsigned rem = sh_remain;
    if (t < 256) hist256[t] = 0u;
    __syncthreads();
    unsigned himask = (pass == 0) ? 0u : (0xFFFFFFFFu << (shift + 8));
    for (int i = t; i < cnt; i += 1024) {
      unsigned kky = cand[i];
      if ((kky & himask) == prefix) atomicAdd(&hist256[(kky >> shift) & 255u], 1u);
    }
    __syncthreads();
    int hv = (t < 256) ? (int)hist256[t] : 0;
    int iv = wave_iscan(hv, lane);
    if (t < 256 && lane == 63) wtB[wid] = iv;
    __syncthreads();
    if (t < 256) {
      int b = 0, tot = 0;
#pragma unroll
      for (int w2 = 0; w2 < 4; ++w2) { int s = wtB[w2]; if (w2 < wid) b += s; tot += s; }
      unsigned val = (unsigned)(iv + b);
      unsigned sstrict = (unsigned)tot - val;
      if (sstrict < rem && sstrict + (unsigned)hv >= rem) {
        sh_prefix = prefix | ((unsigned)t << shift);
        sh_remain = rem - sstrict;
      }
    }
    __syncthreads();
  }
  if (t == 0) {
    outTG[0] = sh_prefix;
    outTG[1] = above + (unsigned)remain - sh_remain;   // Gt = #{key > T}
  }
}

// ---------- grid-parallel compaction (wave-aggregated global atomics) ----------
__global__ void k_sel(const unsigned* __restrict__ key, int n,
                      const unsigned* __restrict__ TG,
                      int* __restrict__ perm, int* __restrict__ cntGt,
                      int* __restrict__ eqbuf, int* __restrict__ cntEq) {
  int i = blockIdx.x * blockDim.x + threadIdx.x;
  int lane = threadIdx.x & 63;
  unsigned long long lmask = (1ull << lane) - 1ull;
  unsigned T = TG[0];
  unsigned kv = (i < n) ? key[i] : 0u;
  bool g = (i < n) && (kv > T);
  bool e = (i < n) && (kv == T);
  unsigned long long mg = __ballot(g);
  unsigned long long me = __ballot(e);
  if (mg) {
    int leader = (int)(__ffsll((long long)mg) - 1);
    int base = 0;
    if (lane == leader) base = atomicAdd(cntGt, (int)__popcll(mg));
    base = __shfl(base, leader, 64);
    if (g) perm[base + (int)__popcll(mg & lmask)] = i;
  }
  if (me) {
    int leader = (int)(__ffsll((long long)me) - 1);
    int base = 0;
    if (lane == leader) base = atomicAdd(cntEq, (int)__popcll(me));
    base = __shfl(base, leader, 64);
    if (e) {
      int p = base + (int)__popcll(me & lmask);
      if (p < MAXEQ) eqbuf[p] = i;
    }
  }
}

// ---------- boundary-equals: pick `need` lowest indices ----------
__global__ void k_sel_eq_fin(const unsigned* __restrict__ TG, const int* __restrict__ eqbuf,
                             const int* __restrict__ cntEq, int* __restrict__ perm, int kk) {
  int lane = threadIdx.x;        // 64
  int G = (int)TG[1];
  int need = kk - G;
  int cnt = *cntEq; if (cnt > MAXEQ) cnt = MAXEQ;
  int prev = -1;
  for (int t = 0; t < need; ++t) {
    int mymin = 0x7fffffff;
    for (int u = lane; u < cnt; u += 64) {
      int v = eqbuf[u];
      if (v > prev && v < mymin) mymin = v;
    }
    for (int o = 1; o < 64; o <<= 1) mymin = min(mymin, __shfl_xor(mymin, o, 64));
    if (lane == 0) perm[G + t] = mymin;
    prev = mymin;
  }
}

// ---------- pooled gather + per-block column-max + fused grid-cell count ----------
template <int R>
__global__ __launch_bounds__(256) void k_pool_pmax(
    const float* __restrict__ x, const float* __restrict__ score,
    const int* __restrict__ perm, const float* __restrict__ pos_in,
    float* __restrict__ xout, float* __restrict__ pos_out, int store,
    float* __restrict__ pmax, int* __restrict__ counts, int Gg, float inv_w) {
  __shared__ float sm[2][HID];
  int f = threadIdx.x & 127;
  int half = threadIdx.x >> 7;
  int j0 = blockIdx.x * R;
  float mx = -1e30f;
  for (int r = half; r < R; r += 2) {
    int j = j0 + r;
    int node = perm[j];
    float v = score[node];
    float val = x[(size_t)node * HID + f] * v;
    if (store) {
      xout[(size_t)j * HID + f] = val;
      if (f == 0) {
        float px = pos_in[node * 2], py = pos_in[node * 2 + 1];
        pos_out[j * 2] = px; pos_out[j * 2 + 1] = py;
        int cx = min(Gg - 1, max(0, (int)(px * inv_w)));
        int cy = min(Gg - 1, max(0, (int)(py * inv_w)));
        atomicAdd(&counts[cy * Gg + cx], 1);
      }
    }
    mx = fmaxf(mx, val);
  }
  sm[half][f] = mx;
  __syncthreads();
  if (half == 0) pmax[blockIdx.x * HID + f] = fmaxf(sm[0][f], sm[1][f]);
}

// ---------- grid scan (1 block over <=4096 cells) ----------
__global__ __launch_bounds__(1024) void k_grid_scan(const int* __restrict__ counts,
                                                    int* __restrict__ starts,
                                                    int* __restrict__ cursor, int cells) {
  __shared__ int wtA[16];
  int t = threadIdx.x;
  int lane = t & 63, wid = t >> 6;
  int c0[4]; int base4 = t * 4; int s = 0;
#pragma unroll
  for (int u = 0; u < 4; ++u) {
    int idx = base4 + u;
    c0[u] = (idx < cells) ? counts[idx] : 0;
    s += c0[u];
  }
  int is = wave_iscan(s, lane);
  if (lane == 63) wtA[wid] = is;
  __syncthreads();
  int b = 0;
#pragma unroll
  for (int w2 = 0; w2 < 16; ++w2) { if (w2 < wid) b += wtA[w2]; }
  int excl = b + is - s;
#pragma unroll
  for (int u = 0; u < 4; ++u) {
    int idx = base4 + u;
    if (idx < cells) { starts[idx] = excl; cursor[idx] = excl; excl += c0[u]; }
  }
}

__global__ void k_grid_scatter(const float2* __restrict__ pos, int m, int Gg, float inv_w,
                               int* __restrict__ cursor, float2* __restrict__ spos,
                               int* __restrict__ sidx) {
  int i = blockIdx.x * blockDim.x + threadIdx.x;
  if (i >= m) return;
  float2 p = pos[i];
  int cx = min(Gg - 1, max(0, (int)(p.x * inv_w)));
  int cy = min(Gg - 1, max(0, (int)(p.y * inv_w)));
  int pp = atomicAdd(&cursor[cy * Gg + cx], 1);
  spos[pp] = p;
  sidx[pp] = i;
}

// ---------- exact KNN, one wave per query ----------
template <int K>
__global__ __launch_bounds__(256) void k_knn_wave(const float2* __restrict__ spos,
                           const int* __restrict__ sidx,
                           const int* __restrict__ starts, const int* __restrict__ counts,
                           int m, int G, float w, float inv_w, int* __restrict__ src_out) {
  int lane = threadIdx.x & 63;
  int j = blockIdx.x * (blockDim.x >> 6) + (threadIdx.x >> 6);
  if (j >= m) return;
  float2 qp = spos[j];
  int q = sidx[j];
  int cx = min(G - 1, max(0, (int)(qp.x * inv_w)));
  int cy = min(G - 1, max(0, (int)(qp.y * inv_w)));

  float bd[K]; int bi[K];
#pragma unroll
  for (int t = 0; t < K; ++t) { bd[t] = 1e30f; bi[t] = 0; }

  auto scan_span = [&](int s, int e) {
    for (int p = s + lane; p < e; p += 64) {
      if (p == j) continue;
      float2 pp = spos[p];
      float dx = qp.x - pp.x, dy = qp.y - pp.y;
      float d = dx * dx + dy * dy;
      if (d < bd[K - 1]) {
        float dd = d; int ii = sidx[p];
#pragma unroll
        for (int t = 0; t < K; ++t) {
          bool sw = dd < bd[t];
          float od = bd[t]; int oi = bi[t];
          if (sw) { bd[t] = dd; bi[t] = ii; dd = od; ii = oi; }
        }
      }
    }
  };

  {
    int xl = max(0, cx - 1), xh = min(G - 1, cx + 1);
    int y0 = max(0, cy - 1), y1 = min(G - 1, cy + 1);
    int ss[3], ee[3]; int nr = 0;
    for (int y = y0; y <= y1; ++y) {
      int b = y * G;
      ss[nr] = starts[b + xl];
      ee[nr] = starts[b + xh] + counts[b + xh];
      ++nr;
    }
    for (int t = 0; t < nr; ++t) scan_span(ss[t], ee[t]);
  }

  int r = 1;
  unsigned long long mg[K];
  while (true) {
    unsigned long long tmp[K];
#pragma unroll
    for (int t = 0; t < K; ++t)
      tmp[t] = ((unsigned long long)__float_as_uint(bd[t]) << 32) | (unsigned)bi[t];
#pragma unroll
    for (int t = 0; t < K; ++t) {
      unsigned long long mn = tmp[0];
#pragma unroll
      for (int o = 1; o < 64; o <<= 1) {
        unsigned long long ot = __shfl_xor(mn, o, 64);
        if (ot < mn) mn = ot;
      }
      mg[t] = mn;
      if (tmp[0] == mn) {
#pragma unroll
        for (int s2 = 0; s2 < K - 1; ++s2) tmp[s2] = tmp[s2 + 1];
        tmp[K - 1] = ~0ull;
      }
    }
    float kth = __uint_as_float((unsigned)(mg[K - 1] >> 32));
    float bnd = 1e30f;
    if (cx - r > 0)     bnd = fminf(bnd, qp.x - (float)(cx - r) * w);
    if (cx + r < G - 1) bnd = fminf(bnd, (float)(cx + r + 1) * w - qp.x);
    if (cy - r > 0)     bnd = fminf(bnd, qp.y - (float)(cy - r) * w);
    if (cy + r < G - 1) bnd = fminf(bnd, (float)(cy + r + 1) * w - qp.y);
    if (bnd > 1e29f) break;
    float bb = fmaxf(bnd, 0.f) * 0.999f;
    if (kth < bb * bb) break;
    ++r;
    int xl = max(0, cx - r), xh = min(G - 1, cx + r);
    int yt = cy - r, yb = cy + r;
    if (yt >= 0)     { int b = yt * G; scan_span(starts[b + xl], starts[b + xh] + counts[b + xh]); }
    if (yb <= G - 1) { int b = yb * G; scan_span(starts[b + xl], starts[b + xh] + counts[b + xh]); }
    int ylo = max(0, cy - r + 1), yhi = min(G - 1, cy + r - 1);
    for (int y = ylo; y <= yhi; ++y) {
      int b = y * G;
      if (cx - r >= 0)     { int c = b + cx - r; scan_span(starts[c], starts[c] + counts[c]); }
      if (cx + r <= G - 1) { int c = b + cx + r; scan_span(starts[c], starts[c] + counts[c]); }
    }
  }
  if (lane == 0) {
#pragma unroll
    for (int t = 0; t < K; ++t) src_out[q * K + t] = (int)(unsigned)(mg[t] & 0xffffffffu);
  }
}

// ---------- grid-parallel pmax reduction: 24 blocks -> pmax2[3][8][HID] ----------
__global__ __launch_bounds__(256) void k_colmax2(const float* __restrict__ pmax,
                                                 int P0, int P1, int P2,
                                                 float* __restrict__ pmax2) {
  __shared__ float sm[2][HID];
  int l = blockIdx.x >> 3, c = blockIdx.x & 7;
  int lo3[3] = {0, P0, P0 + P1};
  int len3[3] = {P0, P1, P2};
  int lo = lo3[l], len = len3[l];
  int f = threadIdx.x & 127, half = threadIdx.x >> 7;
  float mx = -1e30f;
  for (int p = c + 8 * half; p < len; p += 16)
    mx = fmaxf(mx, pmax[(size_t)(lo + p) * HID + f]);
  sm[half][f] = mx;
  __syncthreads();
  if (half == 0) pmax2[(size_t)blockIdx.x * HID + f] = fmaxf(sm[0][f], sm[1][f]);
}

// ---------- final: tiny reduce (24 rows) + MLP head (8-way parallel h1) ----------
__global__ __launch_bounds__(1024) void k_final(const float* __restrict__ pmax2,
                        const float* __restrict__ W1, const float* __restrict__ b1,
                        const float* __restrict__ W2, const float* __restrict__ b2,
                        float* __restrict__ out) {
  __shared__ float sxs[3 * HID];
  __shared__ float red[8][HID];
  __shared__ float h1[HID];
  int f = threadIdx.x & 127, ch = threadIdx.x >> 7;   // 8 channels x 128
  // xs[l*HID+f] = max over 8 partials
  if (ch < 3) {
    float mx = pmax2[(size_t)(ch * 8) * HID + f];
#pragma unroll
    for (int u = 1; u < 8; ++u) mx = fmaxf(mx, pmax2[(size_t)(ch * 8 + u) * HID + f]);
    sxs[ch * HID + f] = mx;
  }
  __syncthreads();
  // h1 = relu(xs @ W1 + b1), split 384 c's across 8 channels
  float acc = 0.f;
  for (int c = ch * 48; c < (ch + 1) * 48; ++c) acc += sxs[c] * W1[c * HID + f];
  red[ch][f] = acc;
  __syncthreads();
  if (ch == 0) {
    float a = b1[f];
#pragma unroll
    for (int u = 0; u < 8; ++u) a += red[u][f];
    h1[f] = a > 0.f ? a : 0.f;
  }
  __syncthreads();
  if (threadIdx.x < 5) {
    float a = b2[threadIdx.x];
    for (int c = 0; c < HID; ++c) a += h1[c] * W2[c * 5 + threadIdx.x];
    out[threadIdx.x] = a;
  }
}

extern "C" void kernel_launch(void* const* d_in, const int* in_sizes, int n_in,
                              void* d_out, int out_size, void* d_ws, size_t ws_size,
                              hipStream_t stream) {
  const float* x_in   = (const float*)d_in[0];
  const float* pos_in = (const float*)d_in[1];
  const int*   ei     = (const int*)d_in[2];
  const float* Wrel   = (const float*)d_in[3];
  const float* brel   = (const float*)d_in[4];
  const float* Wroot  = (const float*)d_in[5];
  const float* Wprel  = (const float*)d_in[6];
  const float* bprel  = (const float*)d_in[7];
  const float* Wproot = (const float*)d_in[8];
  const float* W1     = (const float*)d_in[9];
  const float* b1     = (const float*)d_in[10];
  const float* W2     = (const float*)d_in[11];
  const float* b2     = (const float*)d_in[12];
  float* out = (float*)d_out;

  const int N0 = in_sizes[0] / HID;   // 20000
  const int P0 = (N0 / 2) / PR, P1 = (N0 / 4) / PR, P2 = (N0 / 8) / PR;

  char* w = (char*)d_ws;
  float*    xB     = (float*)w;    w += (size_t)N0 * HID * 4;
  float*    xA     = (float*)w;    w += (size_t)(N0 / 2) * HID * 4;
  float*    score  = (float*)w;    w += (size_t)N0 * 4;
  unsigned* key    = (unsigned*)w; w += (size_t)N0 * 4;
  float*    ubuf   = (float*)w;    w += (size_t)N0 * 4;
  float*    vbuf   = (float*)w;    w += (size_t)N0 * 4;
  float*    posA   = (float*)w;    w += (size_t)(N0 / 2) * 2 * 4;
  float*    posB   = (float*)w;    w += (size_t)(N0 / 2) * 2 * 4;
  int*      srcbuf = (int*)w;      w += (size_t)(N0 / 2) * 8 * 4;
  int*      permb  = (int*)w;      w += (size_t)(N0 / 2) * 4;
  float*    pmax   = (float*)w;    w += (size_t)(P0 + P1 + P2) * HID * 4;
  float*    pmax2  = (float*)w;    w += (size_t)24 * HID * 4;
  // zeroed-together region: [ghist 4KB][cnt 32B][counts 16KB]
  unsigned* ghist  = (unsigned*)w; w += 1024 * 4;
  int*      cnt    = (int*)w;      w += 32;              // cntGt, cntEq, candCnt
  int*      counts = (int*)w;      w += MAXCELLS * 4;
  const size_t ZERO_BYTES = 1024 * 4 + 32 + MAXCELLS * 4;
  unsigned* TG     = (unsigned*)w; w += 16;
  unsigned* BA     = (unsigned*)w; w += 16;
  unsigned* candbuf= (unsigned*)w; w += CAND_CAP * 4;
  int*      eqbuf  = (int*)w;      w += MAXEQ * 4;
  int*      starts = (int*)w;      w += MAXCELLS * 4;
  int*      cursor = (int*)w;      w += MAXCELLS * 4;
  float2*   spos   = (float2*)w;   w += (size_t)(N0 / 2) * 8;
  int*      sidx   = (int*)w;      w += (size_t)(N0 / 2) * 4;
  (void)ws_size; (void)n_in; (void)out_size;

  int n = N0;
  const float* xcur   = x_in;
  const float* poscur = pos_in;
  const int*   srccur = ei;
  int kcur = 6;
  int Poff = 0;

  for (int l = 0; l < 3; ++l) {
    const int kk = n / 2;
    int Gg = (int)ceilf(sqrtf((float)kk / 2.5f));
    if (Gg > 64) Gg = 64;
    if (Gg < 1) Gg = 1;
    int cells = Gg * Gg;
    float cw = 100.f / (float)Gg;
    float inv_w = (float)Gg / 100.f;
    int cblocks = (n + CRPB - 1) / CRPB;

    hipMemsetAsync(ghist, 0, ZERO_BYTES, stream);   // ghist + cnt + counts

    if (kcur == 6) {
      k_conv_fused<6><<<cblocks, 256, 0, stream>>>(xcur, srccur, n, 1.f / 6.f,
          Wrel + l * HID * HID, Wroot + l * HID * HID, brel + l * HID,
          Wprel + l * HID, Wproot + l * HID, xB, ubuf, vbuf);
      k_score_lite<6><<<(n + 255) / 256, 256, 0, stream>>>(ubuf, vbuf, srccur, bprel + l,
                                                           n, score, key);
    } else {
      k_conv_fused<8><<<cblocks, 256, 0, stream>>>(xcur, srccur, n, 1.f / 8.f,
          Wrel + l * HID * HID, Wroot + l * HID * HID, brel + l * HID,
          Wprel + l * HID, Wproot + l * HID, xB, ubuf, vbuf);
      k_score_lite<8><<<(n + 255) / 256, 256, 0, stream>>>(ubuf, vbuf, srccur, bprel + l,
                                                           n, score, key);
    }
    int n4 = n >> 2;
    k_hist<<<(n4 + 127) / 128, 128, 0, stream>>>(key, n4, ghist);
    k_pickbin<<<1, 1024, 0, stream>>>(ghist, kk, BA);
    k_collect<<<(n + 255) / 256, 256, 0, stream>>>(key, n, BA, candbuf, cnt + 2);
    k_refine<<<1, 1024, 0, stream>>>(candbuf, cnt + 2, BA, kk, TG);
    k_sel<<<(n + 255) / 256, 256, 0, stream>>>(key, n, TG, permb, cnt, eqbuf, cnt + 1);
    k_sel_eq_fin<<<1, 64, 0, stream>>>(TG, eqbuf, cnt + 1, permb, kk);

    float* pos_out = (l == 0) ? posA : posB;
    int store = (l < 2) ? 1 : 0;
    k_pool_pmax<PR><<<kk / PR, 256, 0, stream>>>(xB, score, permb, poscur, xA, pos_out,
                                                 store, pmax + (size_t)Poff * HID,
                                                 counts, Gg, inv_w);
    Poff += kk / PR;
    n = kk;
    if (l < 2) {
      k_grid_scan<<<1, 1024, 0, stream>>>(counts, starts, cursor, cells);
      k_grid_scatter<<<(n + 255) / 256, 256, 0, stream>>>((const float2*)pos_out, n, Gg, inv_w,
                                                          cursor, spos, sidx);
      if (l == 0) { k_knn_wave<6><<<(n + 3) / 4, 256, 0, stream>>>(spos, sidx, starts, counts,
                                                                   n, Gg, cw, inv_w, srcbuf); kcur = 6; }
      else        { k_knn_wave<8><<<(n + 3) / 4, 256, 0, stream>>>(spos, sidx, starts, counts,
                                                                   n, Gg, cw, inv_w, srcbuf); kcur = 8; }
    }
    xcur = xA; poscur = pos_out; srccur = srcbuf;
  }
  k_colmax2<<<24, 256, 0, stream>>>(pmax, P0, P1, P2, pmax2);
  k_final<<<1, 1024, 0, stream>>>(pmax2, W1, b1, W2, b2, out);
}

// Round 17
// 252.959 us; speedup vs baseline: 1.5578x; 1.0529x over previous
//
#include <hip/hip_runtime.h>
#include <hip/hip_bf16.h>
#include <math.h>

#define HID 128
#define PR 20      // rows per pool block
#define CRPB 32    // conv rows per block
#define CAND_CAP 8192
#define MAXEQ 8192
#define MAXCELLS 4096

__device__ inline int wave_iscan(int v, int lane) {   // inclusive scan within 64-lane wave
#pragma unroll
  for (int off = 1; off < 64; off <<= 1) {
    int o = __shfl_up(v, off, 64);
    if (lane >= off) v += o;
  }
  return v;
}

// ---------- fused mean-gather + GraphConv + score-scalar epilogue ----------
template <int K>
__global__ __launch_bounds__(256) void k_conv_fused(
    const float* __restrict__ x, const int* __restrict__ src, int n, float invk,
    const float* __restrict__ Wrel, const float* __restrict__ Wroot,
    const float* __restrict__ brel,
    const float* __restrict__ wprel, const float* __restrict__ wproot,
    float* __restrict__ out, float* __restrict__ uo, float* __restrict__ vo) {
  __shared__ float4 sagg4[CRPB][HID / 4];
  __shared__ float4 sx4[CRPB][HID / 4];
  __shared__ int ssrc[CRPB * K];
  int t = threadIdx.x;
  int i0 = blockIdx.x * CRPB;
  const int nK = n * K;
  for (int s = t; s < CRPB * K; s += 256) {
    int gi = i0 * K + s;
    int v = (gi < nK) ? src[gi] : 0;
    ssrc[s] = ((unsigned)v < (unsigned)n) ? v : 0;
  }
  __syncthreads();
  {
    int fq = t & 31, h = t >> 5;
    const float4* x4 = (const float4*)x;
    for (int r = h; r < CRPB; r += 8) {
      int row = i0 + r;
      float4 s = make_float4(0.f, 0.f, 0.f, 0.f);
      float4 xv = make_float4(0.f, 0.f, 0.f, 0.f);
      if (row < n) {
#pragma unroll
        for (int j = 0; j < K; ++j) {
          float4 xx = x4[(size_t)ssrc[r * K + j] * 32 + fq];
          s.x += xx.x; s.y += xx.y; s.z += xx.z; s.w += xx.w;
        }
        xv = x4[(size_t)row * 32 + fq];
      }
      s.x *= invk; s.y *= invk; s.z *= invk; s.w *= invk;
      sagg4[r][fq] = s;
      sx4[r][fq] = xv;
    }
  }
  __syncthreads();
  int q = t & 31, rg = t >> 5;
  const float4* Wrel4  = (const float4*)Wrel;
  const float4* Wroot4 = (const float4*)Wroot;
  float4 bq = ((const float4*)brel)[q];
  float4 acc[4];
#pragma unroll
  for (int rr = 0; rr < 4; ++rr) acc[rr] = bq;
  int rbase = rg * 4;
#pragma unroll 2
  for (int cq = 0; cq < HID / 4; ++cq) {
    float4 w1[4], w2[4];
#pragma unroll
    for (int uu = 0; uu < 4; ++uu) {
      w1[uu] = Wrel4[(cq * 4 + uu) * 32 + q];
      w2[uu] = Wroot4[(cq * 4 + uu) * 32 + q];
    }
#pragma unroll
    for (int rr = 0; rr < 4; ++rr) {
      float4 a  = sagg4[rbase + rr][cq];
      float4 xx = sx4[rbase + rr][cq];
      acc[rr].x += a.x*w1[0].x + a.y*w1[1].x + a.z*w1[2].x + a.w*w1[3].x
                 + xx.x*w2[0].x + xx.y*w2[1].x + xx.z*w2[2].x + xx.w*w2[3].x;
      acc[rr].y += a.x*w1[0].y + a.y*w1[1].y + a.z*w1[2].y + a.w*w1[3].y
                 + xx.x*w2[0].y + xx.y*w2[1].y + xx.z*w2[2].y + xx.w*w2[3].y;
      acc[rr].z += a.x*w1[0].z + a.y*w1[1].z + a.z*w1[2].z + a.w*w1[3].z
                 + xx.x*w2[0].z + xx.y*w2[1].z + xx.z*w2[2].z + xx.w*w2[3].z;
      acc[rr].w += a.x*w1[0].w + a.y*w1[1].w + a.z*w1[2].w + a.w*w1[3].w
                 + xx.x*w2[0].w + xx.y*w2[1].w + xx.z*w2[2].w + xx.w*w2[3].w;
    }
  }
  float4 wplq = ((const float4*)wprel)[q];
  float4 wprq = ((const float4*)wproot)[q];
#pragma unroll
  for (int rr = 0; rr < 4; ++rr) {
    int row = i0 + rbase + rr;
    float4 v = acc[rr];
    v.x = v.x > 0.f ? v.x : 0.f;
    v.y = v.y > 0.f ? v.y : 0.f;
    v.z = v.z > 0.f ? v.z : 0.f;
    v.w = v.w > 0.f ? v.w : 0.f;
    float pu = 0.f, pv = 0.f;
    if (row < n) {
      ((float4*)out)[(size_t)row * 32 + q] = v;
      pu = v.x * wplq.x + v.y * wplq.y + v.z * wplq.z + v.w * wplq.w;
      pv = v.x * wprq.x + v.y * wprq.y + v.z * wprq.z + v.w * wprq.w;
    }
#pragma unroll
    for (int o = 16; o; o >>= 1) {
      pu += __shfl_down(pu, o, 32);
      pv += __shfl_down(pv, o, 32);
    }
    if (q == 0 && row < n) { uo[row] = pu; vo[row] = pv; }
  }
}

// ---------- scalar score + fused per-block 1024-bin histogram ----------
template <int K>
__global__ __launch_bounds__(256) void k_score_lite(
    const float* __restrict__ u, const float* __restrict__ v,
    const int* __restrict__ src, const float* __restrict__ bprel,
    int n, float* __restrict__ score, unsigned* __restrict__ key,
    unsigned* __restrict__ ghist) {
  __shared__ unsigned lh[1024];
  int t = threadIdx.x;
#pragma unroll
  for (int uu = 0; uu < 4; ++uu) lh[t + uu * 256] = 0u;
  __syncthreads();
  int i = blockIdx.x * 256 + t;
  if (i < n) {
    float s = v[i] + bprel[0];
#pragma unroll
    for (int j = 0; j < K; ++j) s += u[src[i * K + j]];
    float sc = tanhf(s);
    score[i] = sc;
    unsigned bb = __float_as_uint(sc);
    unsigned k2 = (bb & 0x80000000u) ? ~bb : (bb | 0x80000000u);
    key[i] = k2;
    atomicAdd(&lh[k2 >> 22], 1u);
  }
  __syncthreads();
#pragma unroll
  for (int uu = 0; uu < 4; ++uu) {
    unsigned vv = lh[t + uu * 256];
    if (vv) atomicAdd(&ghist[t + uu * 256], vv);
  }
}

// ---------- collect: inline boundary-bin pick (per-block) + candidate append ----------
__global__ __launch_bounds__(256) void k_collect(
    const unsigned* __restrict__ key, int n, int kk,
    const unsigned* __restrict__ ghist,
    unsigned* __restrict__ BA, unsigned* __restrict__ candbuf, int* __restrict__ candCnt) {
  __shared__ int wt[4];
  __shared__ unsigned shB, shAbove;
  int t = threadIdx.x;             // 256
  int lane = t & 63, wid = t >> 6;
  // each thread owns 4 consecutive bins
  unsigned h[4]; int s = 0;
#pragma unroll
  for (int uu = 0; uu < 4; ++uu) { h[uu] = ghist[t * 4 + uu]; s += (int)h[uu]; }
  int is = wave_iscan(s, lane);
  if (lane == 63) wt[wid] = is;
  __syncthreads();
  int b = 0, tot = 0;
#pragma unroll
  for (int w2 = 0; w2 < 4; ++w2) { int ss = wt[w2]; if (w2 < wid) b += ss; tot += ss; }
  int c = b + is - s;              // exclusive prefix before this thread's bins
#pragma unroll
  for (int uu = 0; uu < 4; ++uu) {
    c += (int)h[uu];
    unsigned above_strict = (unsigned)(tot - c);
    unsigned above_incl = above_strict + h[uu];
    if (above_incl >= (unsigned)kk && above_strict < (unsigned)kk) {
      shB = (unsigned)(t * 4 + uu);
      shAbove = above_strict;
    }
  }
  __syncthreads();
  unsigned B = shB;
  if (blockIdx.x == 0 && t == 0) { BA[0] = B; BA[1] = shAbove; }
  // ballot-aggregated candidate append
  int i = blockIdx.x * 256 + t;
  unsigned long long lmask = (1ull << lane) - 1ull;
  unsigned kv = (i < n) ? key[i] : 0u;
  bool m = (i < n) && ((kv >> 22) == B);
  unsigned long long mm = __ballot(m);
  if (mm) {
    int leader = (int)(__ffsll((long long)mm) - 1);
    int base = 0;
    if (lane == leader) base = atomicAdd(candCnt, (int)__popcll(mm));
    base = __shfl(base, leader, 64);
    if (m) {
      int p = base + (int)__popcll(mm & lmask);
      if (p < CAND_CAP) candbuf[p] = kv;
    }
  }
}

// ---------- refine over candidates (LDS-staged, <=8K) -> T, Gt ----------
__global__ __launch_bounds__(1024) void k_refine(const unsigned* __restrict__ candbuf,
                                                 const int* __restrict__ candCnt,
                                                 const unsigned* __restrict__ BA, int kk,
                                                 unsigned* __restrict__ outTG) {
  __shared__ unsigned cand[CAND_CAP];
  __shared__ unsigned hist256[256];
  __shared__ unsigned sh_remain, sh_prefix;
  __shared__ int wtB[4];
  int t = threadIdx.x;
  int lane = t & 63, wid = t >> 6;
  unsigned above = BA[1];
  int remain = kk - (int)above;
  int cnt = *candCnt; if (cnt > CAND_CAP) cnt = CAND_CAP;
  for (int i = t; i < cnt; i += 1024) cand[i] = candbuf[i];
  if (t == 0) { sh_prefix = 0u; sh_remain = (unsigned)remain; }
  __syncthreads();
  for (int pass = 0; pass < 4; ++pass) {
    int shift = 24 - pass * 8;
    unsigned prefix = sh_prefix;
    unsigned rem = sh_remain;
    if (t < 256) hist256[t] = 0u;
    __syncthreads();
    unsigned himask = (pass == 0) ? 0u : (0xFFFFFFFFu << (shift + 8));
    for (int i = t; i < cnt; i += 1024) {
      unsigned kky = cand[i];
      if ((kky & himask) == prefix) atomicAdd(&hist256[(kky >> shift) & 255u], 1u);
    }
    __syncthreads();
    int hv = (t < 256) ? (int)hist256[t] : 0;
    int iv = wave_iscan(hv, lane);
    if (t < 256 && lane == 63) wtB[wid] = iv;
    __syncthreads();
    if (t < 256) {
      int b = 0, tot = 0;
#pragma unroll
      for (int w2 = 0; w2 < 4; ++w2) { int s = wtB[w2]; if (w2 < wid) b += s; tot += s; }
      unsigned val = (unsigned)(iv + b);
      unsigned sstrict = (unsigned)tot - val;
      if (sstrict < rem && sstrict + (unsigned)hv >= rem) {
        sh_prefix = prefix | ((unsigned)t << shift);
        sh_remain = rem - sstrict;
      }
    }
    __syncthreads();
  }
  if (t == 0) {
    outTG[0] = sh_prefix;
    outTG[1] = above + (unsigned)remain - sh_remain;   // Gt = #{key > T}
  }
}

// ---------- grid-parallel compaction (wave-aggregated global atomics) ----------
__global__ void k_sel(const unsigned* __restrict__ key, int n,
                      const unsigned* __restrict__ TG,
                      int* __restrict__ perm, int* __restrict__ cntGt,
                      int* __restrict__ eqbuf, int* __restrict__ cntEq) {
  int i = blockIdx.x * blockDim.x + threadIdx.x;
  int lane = threadIdx.x & 63;
  unsigned long long lmask = (1ull << lane) - 1ull;
  unsigned T = TG[0];
  unsigned kv = (i < n) ? key[i] : 0u;
  bool g = (i < n) && (kv > T);
  bool e = (i < n) && (kv == T);
  unsigned long long mg = __ballot(g);
  unsigned long long me = __ballot(e);
  if (mg) {
    int leader = (int)(__ffsll((long long)mg) - 1);
    int base = 0;
    if (lane == leader) base = atomicAdd(cntGt, (int)__popcll(mg));
    base = __shfl(base, leader, 64);
    if (g) perm[base + (int)__popcll(mg & lmask)] = i;
  }
  if (me) {
    int leader = (int)(__ffsll((long long)me) - 1);
    int base = 0;
    if (lane == leader) base = atomicAdd(cntEq, (int)__popcll(me));
    base = __shfl(base, leader, 64);
    if (e) {
      int p = base + (int)__popcll(me & lmask);
      if (p < MAXEQ) eqbuf[p] = i;
    }
  }
}

// ---------- boundary-equals: pick `need` lowest indices ----------
__global__ void k_sel_eq_fin(const unsigned* __restrict__ TG, const int* __restrict__ eqbuf,
                             const int* __restrict__ cntEq, int* __restrict__ perm, int kk) {
  int lane = threadIdx.x;        // 64
  int G = (int)TG[1];
  int need = kk - G;
  int cnt = *cntEq; if (cnt > MAXEQ) cnt = MAXEQ;
  int prev = -1;
  for (int t = 0; t < need; ++t) {
    int mymin = 0x7fffffff;
    for (int u = lane; u < cnt; u += 64) {
      int v = eqbuf[u];
      if (v > prev && v < mymin) mymin = v;
    }
    for (int o = 1; o < 64; o <<= 1) mymin = min(mymin, __shfl_xor(mymin, o, 64));
    if (lane == 0) perm[G + t] = mymin;
    prev = mymin;
  }
}

// ---------- pooled gather + per-block column-max + fused grid-cell count ----------
template <int R>
__global__ __launch_bounds__(256) void k_pool_pmax(
    const float* __restrict__ x, const float* __restrict__ score,
    const int* __restrict__ perm, const float* __restrict__ pos_in,
    float* __restrict__ xout, float* __restrict__ pos_out, int store,
    float* __restrict__ pmax, int* __restrict__ counts, int Gg, float inv_w) {
  __shared__ float sm[2][HID];
  int f = threadIdx.x & 127;
  int half = threadIdx.x >> 7;
  int j0 = blockIdx.x * R;
  float mx = -1e30f;
  for (int r = half; r < R; r += 2) {
    int j = j0 + r;
    int node = perm[j];
    float v = score[node];
    float val = x[(size_t)node * HID + f] * v;
    if (store) {
      xout[(size_t)j * HID + f] = val;
      if (f == 0) {
        float px = pos_in[node * 2], py = pos_in[node * 2 + 1];
        pos_out[j * 2] = px; pos_out[j * 2 + 1] = py;
        int cx = min(Gg - 1, max(0, (int)(px * inv_w)));
        int cy = min(Gg - 1, max(0, (int)(py * inv_w)));
        atomicAdd(&counts[cy * Gg + cx], 1);
      }
    }
    mx = fmaxf(mx, val);
  }
  sm[half][f] = mx;
  __syncthreads();
  if (half == 0) pmax[blockIdx.x * HID + f] = fmaxf(sm[0][f], sm[1][f]);
}

// ---------- grid scan (1 block over <=4096 cells) ----------
__global__ __launch_bounds__(1024) void k_grid_scan(const int* __restrict__ counts,
                                                    int* __restrict__ starts,
                                                    int* __restrict__ cursor, int cells) {
  __shared__ int wtA[16];
  int t = threadIdx.x;
  int lane = t & 63, wid = t >> 6;
  int c0[4]; int base4 = t * 4; int s = 0;
#pragma unroll
  for (int u = 0; u < 4; ++u) {
    int idx = base4 + u;
    c0[u] = (idx < cells) ? counts[idx] : 0;
    s += c0[u];
  }
  int is = wave_iscan(s, lane);
  if (lane == 63) wtA[wid] = is;
  __syncthreads();
  int b = 0;
#pragma unroll
  for (int w2 = 0; w2 < 16; ++w2) { if (w2 < wid) b += wtA[w2]; }
  int excl = b + is - s;
#pragma unroll
  for (int u = 0; u < 4; ++u) {
    int idx = base4 + u;
    if (idx < cells) { starts[idx] = excl; cursor[idx] = excl; excl += c0[u]; }
  }
}

__global__ void k_grid_scatter(const float2* __restrict__ pos, int m, int Gg, float inv_w,
                               int* __restrict__ cursor, float2* __restrict__ spos,
                               int* __restrict__ sidx) {
  int i = blockIdx.x * blockDim.x + threadIdx.x;
  if (i >= m) return;
  float2 p = pos[i];
  int cx = min(Gg - 1, max(0, (int)(p.x * inv_w)));
  int cy = min(Gg - 1, max(0, (int)(p.y * inv_w)));
  int pp = atomicAdd(&cursor[cy * Gg + cx], 1);
  spos[pp] = p;
  sidx[pp] = i;
}

// ---------- exact KNN, one wave per query ----------
template <int K>
__global__ __launch_bounds__(256) void k_knn_wave(const float2* __restrict__ spos,
                           const int* __restrict__ sidx,
                           const int* __restrict__ starts, const int* __restrict__ counts,
                           int m, int G, float w, float inv_w, int* __restrict__ src_out) {
  int lane = threadIdx.x & 63;
  int j = blockIdx.x * (blockDim.x >> 6) + (threadIdx.x >> 6);
  if (j >= m) return;
  float2 qp = spos[j];
  int q = sidx[j];
  int cx = min(G - 1, max(0, (int)(qp.x * inv_w)));
  int cy = min(G - 1, max(0, (int)(qp.y * inv_w)));

  float bd[K]; int bi[K];
#pragma unroll
  for (int t = 0; t < K; ++t) { bd[t] = 1e30f; bi[t] = 0; }

  auto scan_span = [&](int s, int e) {
    for (int p = s + lane; p < e; p += 64) {
      if (p == j) continue;
      float2 pp = spos[p];
      float dx = qp.x - pp.x, dy = qp.y - pp.y;
      float d = dx * dx + dy * dy;
      if (d < bd[K - 1]) {
        float dd = d; int ii = sidx[p];
#pragma unroll
        for (int t = 0; t < K; ++t) {
          bool sw = dd < bd[t];
          float od = bd[t]; int oi = bi[t];
          if (sw) { bd[t] = dd; bi[t] = ii; dd = od; ii = oi; }
        }
      }
    }
  };

  {
    int xl = max(0, cx - 1), xh = min(G - 1, cx + 1);
    int y0 = max(0, cy - 1), y1 = min(G - 1, cy + 1);
    int ss[3], ee[3]; int nr = 0;
    for (int y = y0; y <= y1; ++y) {
      int b = y * G;
      ss[nr] = starts[b + xl];
      ee[nr] = starts[b + xh] + counts[b + xh];
      ++nr;
    }
    for (int t = 0; t < nr; ++t) scan_span(ss[t], ee[t]);
  }

  int r = 1;
  unsigned long long mg[K];
  while (true) {
    unsigned long long tmp[K];
#pragma unroll
    for (int t = 0; t < K; ++t)
      tmp[t] = ((unsigned long long)__float_as_uint(bd[t]) << 32) | (unsigned)bi[t];
#pragma unroll
    for (int t = 0; t < K; ++t) {
      unsigned long long mn = tmp[0];
#pragma unroll
      for (int o = 1; o < 64; o <<= 1) {
        unsigned long long ot = __shfl_xor(mn, o, 64);
        if (ot < mn) mn = ot;
      }
      mg[t] = mn;
      if (tmp[0] == mn) {
#pragma unroll
        for (int s2 = 0; s2 < K - 1; ++s2) tmp[s2] = tmp[s2 + 1];
        tmp[K - 1] = ~0ull;
      }
    }
    float kth = __uint_as_float((unsigned)(mg[K - 1] >> 32));
    float bnd = 1e30f;
    if (cx - r > 0)     bnd = fminf(bnd, qp.x - (float)(cx - r) * w);
    if (cx + r < G - 1) bnd = fminf(bnd, (float)(cx + r + 1) * w - qp.x);
    if (cy - r > 0)     bnd = fminf(bnd, qp.y - (float)(cy - r) * w);
    if (cy + r < G - 1) bnd = fminf(bnd, (float)(cy + r + 1) * w - qp.y);
    if (bnd > 1e29f) break;
    float bb = fmaxf(bnd, 0.f) * 0.999f;
    if (kth < bb * bb) break;
    ++r;
    int xl = max(0, cx - r), xh = min(G - 1, cx + r);
    int yt = cy - r, yb = cy + r;
    if (yt >= 0)     { int b = yt * G; scan_span(starts[b + xl], starts[b + xh] + counts[b + xh]); }
    if (yb <= G - 1) { int b = yb * G; scan_span(starts[b + xl], starts[b + xh] + counts[b + xh]); }
    int ylo = max(0, cy - r + 1), yhi = min(G - 1, cy + r - 1);
    for (int y = ylo; y <= yhi; ++y) {
      int b = y * G;
      if (cx - r >= 0)     { int c = b + cx - r; scan_span(starts[c], starts[c] + counts[c]); }
      if (cx + r <= G - 1) { int c = b + cx + r; scan_span(starts[c], starts[c] + counts[c]); }
    }
  }
  if (lane == 0) {
#pragma unroll
    for (int t = 0; t < K; ++t) src_out[q * K + t] = (int)(unsigned)(mg[t] & 0xffffffffu);
  }
}

// ---------- grid-parallel pmax reduction: 24 blocks -> pmax2[3][8][HID] ----------
__global__ __launch_bounds__(256) void k_colmax2(const float* __restrict__ pmax,
                                                 int P0, int P1, int P2,
                                                 float* __restrict__ pmax2) {
  __shared__ float sm[2][HID];
  int l = blockIdx.x >> 3, c = blockIdx.x & 7;
  int lo3[3] = {0, P0, P0 + P1};
  int len3[3] = {P0, P1, P2};
  int lo = lo3[l], len = len3[l];
  int f = threadIdx.x & 127, half = threadIdx.x >> 7;
  float mx = -1e30f;
  for (int p = c + 8 * half; p < len; p += 16)
    mx = fmaxf(mx, pmax[(size_t)(lo + p) * HID + f]);
  sm[half][f] = mx;
  __syncthreads();
  if (half == 0) pmax2[(size_t)blockIdx.x * HID + f] = fmaxf(sm[0][f], sm[1][f]);
}

// ---------- final: tiny reduce (24 rows) + MLP head (8-way parallel h1) ----------
__global__ __launch_bounds__(1024) void k_final(const float* __restrict__ pmax2,
                        const float* __restrict__ W1, const float* __restrict__ b1,
                        const float* __restrict__ W2, const float* __restrict__ b2,
                        float* __restrict__ out) {
  __shared__ float sxs[3 * HID];
  __shared__ float red[8][HID];
  __shared__ float h1[HID];
  int f = threadIdx.x & 127, ch = threadIdx.x >> 7;   // 8 channels x 128
  if (ch < 3) {
    float mx = pmax2[(size_t)(ch * 8) * HID + f];
#pragma unroll
    for (int u = 1; u < 8; ++u) mx = fmaxf(mx, pmax2[(size_t)(ch * 8 + u) * HID + f]);
    sxs[ch * HID + f] = mx;
  }
  __syncthreads();
  float acc = 0.f;
  for (int c = ch * 48; c < (ch + 1) * 48; ++c) acc += sxs[c] * W1[c * HID + f];
  red[ch][f] = acc;
  __syncthreads();
  if (ch == 0) {
    float a = b1[f];
#pragma unroll
    for (int u = 0; u < 8; ++u) a += red[u][f];
    h1[f] = a > 0.f ? a : 0.f;
  }
  __syncthreads();
  if (threadIdx.x < 5) {
    float a = b2[threadIdx.x];
    for (int c = 0; c < HID; ++c) a += h1[c] * W2[c * 5 + threadIdx.x];
    out[threadIdx.x] = a;
  }
}

extern "C" void kernel_launch(void* const* d_in, const int* in_sizes, int n_in,
                              void* d_out, int out_size, void* d_ws, size_t ws_size,
                              hipStream_t stream) {
  const float* x_in   = (const float*)d_in[0];
  const float* pos_in = (const float*)d_in[1];
  const int*   ei     = (const int*)d_in[2];
  const float* Wrel   = (const float*)d_in[3];
  const float* brel   = (const float*)d_in[4];
  const float* Wroot  = (const float*)d_in[5];
  const float* Wprel  = (const float*)d_in[6];
  const float* bprel  = (const float*)d_in[7];
  const float* Wproot = (const float*)d_in[8];
  const float* W1     = (const float*)d_in[9];
  const float* b1     = (const float*)d_in[10];
  const float* W2     = (const float*)d_in[11];
  const float* b2     = (const float*)d_in[12];
  float* out = (float*)d_out;

  const int N0 = in_sizes[0] / HID;   // 20000
  const int P0 = (N0 / 2) / PR, P1 = (N0 / 4) / PR, P2 = (N0 / 8) / PR;

  char* w = (char*)d_ws;
  float*    xB     = (float*)w;    w += (size_t)N0 * HID * 4;
  float*    xA     = (float*)w;    w += (size_t)(N0 / 2) * HID * 4;
  float*    score  = (float*)w;    w += (size_t)N0 * 4;
  unsigned* key    = (unsigned*)w; w += (size_t)N0 * 4;
  float*    ubuf   = (float*)w;    w += (size_t)N0 * 4;
  float*    vbuf   = (float*)w;    w += (size_t)N0 * 4;
  float*    posA   = (float*)w;    w += (size_t)(N0 / 2) * 2 * 4;
  float*    posB   = (float*)w;    w += (size_t)(N0 / 2) * 2 * 4;
  int*      srcbuf = (int*)w;      w += (size_t)(N0 / 2) * 8 * 4;
  int*      permb  = (int*)w;      w += (size_t)(N0 / 2) * 4;
  float*    pmax   = (float*)w;    w += (size_t)(P0 + P1 + P2) * HID * 4;
  float*    pmax2  = (float*)w;    w += (size_t)24 * HID * 4;
  // single zeroed region: [ghist 3x4KB][cnt 12 ints + pad][counts 2x16KB]
  unsigned* ghistB = (unsigned*)w; w += 3 * 1024 * 4;
  int*      cnt    = (int*)w;      w += 16 * 4;
  int*      countsB= (int*)w;      w += 2 * MAXCELLS * 4;
  const size_t ZERO_BYTES = 3 * 1024 * 4 + 16 * 4 + 2 * MAXCELLS * 4;
  unsigned* TG     = (unsigned*)w; w += 16;
  unsigned* BA     = (unsigned*)w; w += 16;
  unsigned* candbuf= (unsigned*)w; w += CAND_CAP * 4;
  int*      eqbuf  = (int*)w;      w += MAXEQ * 4;
  int*      starts = (int*)w;      w += MAXCELLS * 4;
  int*      cursor = (int*)w;      w += MAXCELLS * 4;
  float2*   spos   = (float2*)w;   w += (size_t)(N0 / 2) * 8;
  int*      sidx   = (int*)w;      w += (size_t)(N0 / 2) * 4;
  (void)ws_size; (void)n_in; (void)out_size;

  hipMemsetAsync(ghistB, 0, ZERO_BYTES, stream);   // one upfront zeroing

  int n = N0;
  const float* xcur   = x_in;
  const float* poscur = pos_in;
  const int*   srccur = ei;
  int kcur = 6;
  int Poff = 0;

  for (int l = 0; l < 3; ++l) {
    const int kk = n / 2;
    int Gg = (int)ceilf(sqrtf((float)kk / 2.5f));
    if (Gg > 64) Gg = 64;
    if (Gg < 1) Gg = 1;
    int cells = Gg * Gg;
    float cw = 100.f / (float)Gg;
    float inv_w = (float)Gg / 100.f;
    int cblocks = (n + CRPB - 1) / CRPB;
    unsigned* ghist = ghistB + l * 1024;
    int* counts = countsB + (l < 2 ? l : 0) * MAXCELLS;

    if (kcur == 6) {
      k_conv_fused<6><<<cblocks, 256, 0, stream>>>(xcur, srccur, n, 1.f / 6.f,
          Wrel + l * HID * HID, Wroot + l * HID * HID, brel + l * HID,
          Wprel + l * HID, Wproot + l * HID, xB, ubuf, vbuf);
      k_score_lite<6><<<(n + 255) / 256, 256, 0, stream>>>(ubuf, vbuf, srccur, bprel + l,
                                                           n, score, key, ghist);
    } else {
      k_conv_fused<8><<<cblocks, 256, 0, stream>>>(xcur, srccur, n, 1.f / 8.f,
          Wrel + l * HID * HID, Wroot + l * HID * HID, brel + l * HID,
          Wprel + l * HID, Wproot + l * HID, xB, ubuf, vbuf);
      k_score_lite<8><<<(n + 255) / 256, 256, 0, stream>>>(ubuf, vbuf, srccur, bprel + l,
                                                           n, score, key, ghist);
    }
    k_collect<<<(n + 255) / 256, 256, 0, stream>>>(key, n, kk, ghist, BA, candbuf, cnt + 3 * l + 2);
    k_refine<<<1, 1024, 0, stream>>>(candbuf, cnt + 3 * l + 2, BA, kk, TG);
    k_sel<<<(n + 255) / 256, 256, 0, stream>>>(key, n, TG, permb, cnt + 3 * l, eqbuf, cnt + 3 * l + 1);
    k_sel_eq_fin<<<1, 64, 0, stream>>>(TG, eqbuf, cnt + 3 * l + 1, permb, kk);

    float* pos_out = (l == 0) ? posA : posB;
    int store = (l < 2) ? 1 : 0;
    k_pool_pmax<PR><<<kk / PR, 256, 0, stream>>>(xB, score, permb, poscur, xA, pos_out,
                                                 store, pmax + (size_t)Poff * HID,
                                                 counts, Gg, inv_w);
    Poff += kk / PR;
    n = kk;
    if (l < 2) {
      k_grid_scan<<<1, 1024, 0, stream>>>(counts, starts, cursor, cells);
      k_grid_scatter<<<(n + 255) / 256, 256, 0, stream>>>((const float2*)pos_out, n, Gg, inv_w,
                                                          cursor, spos, sidx);
      if (l == 0) { k_knn_wave<6><<<(n + 3) / 4, 256, 0, stream>>>(spos, sidx, starts, counts,
                                                                   n, Gg, cw, inv_w, srcbuf); kcur = 6; }
      else        { k_knn_wave<8><<<(n + 3) / 4, 256, 0, stream>>>(spos, sidx, starts, counts,
                                                                   n, Gg, cw, inv_w, srcbuf); kcur = 8; }
    }
    xcur = xA; poscur = pos_out; srccur = srcbuf;
  }
  k_colmax2<<<24, 256, 0, stream>>>(pmax, P0, P1, P2, pmax2);
  k_final<<<1, 1024, 0, stream>>>(pmax2, W1, b1, W2, b2, out);
}

// Round 18
// 247.077 us; speedup vs baseline: 1.5949x; 1.0238x over previous
//
#include <hip/hip_runtime.h>
#include <hip/hip_bf16.h>
#include <math.h>

#define HID 128
#define PR 20      // rows per pool block
#define CRPB 32    // conv rows per block
#define CAND_CAP 8192
#define MAXCELLS 4096

__device__ inline int wave_iscan(int v, int lane) {   // inclusive scan within 64-lane wave
#pragma unroll
  for (int off = 1; off < 64; off <<= 1) {
    int o = __shfl_up(v, off, 64);
    if (lane >= off) v += o;
  }
  return v;
}

// ---------- fused mean-gather + GraphConv + score-scalar epilogue ----------
template <int K>
__global__ __launch_bounds__(256) void k_conv_fused(
    const float* __restrict__ x, const int* __restrict__ src, int n, float invk,
    const float* __restrict__ Wrel, const float* __restrict__ Wroot,
    const float* __restrict__ brel,
    const float* __restrict__ wprel, const float* __restrict__ wproot,
    float* __restrict__ out, float* __restrict__ uo, float* __restrict__ vo) {
  __shared__ float4 sagg4[CRPB][HID / 4];
  __shared__ float4 sx4[CRPB][HID / 4];
  __shared__ int ssrc[CRPB * K];
  int t = threadIdx.x;
  int i0 = blockIdx.x * CRPB;
  const int nK = n * K;
  for (int s = t; s < CRPB * K; s += 256) {
    int gi = i0 * K + s;
    int v = (gi < nK) ? src[gi] : 0;
    ssrc[s] = ((unsigned)v < (unsigned)n) ? v : 0;
  }
  __syncthreads();
  {
    int fq = t & 31, h = t >> 5;
    const float4* x4 = (const float4*)x;
    for (int r = h; r < CRPB; r += 8) {
      int row = i0 + r;
      float4 s = make_float4(0.f, 0.f, 0.f, 0.f);
      float4 xv = make_float4(0.f, 0.f, 0.f, 0.f);
      if (row < n) {
#pragma unroll
        for (int j = 0; j < K; ++j) {
          float4 xx = x4[(size_t)ssrc[r * K + j] * 32 + fq];
          s.x += xx.x; s.y += xx.y; s.z += xx.z; s.w += xx.w;
        }
        xv = x4[(size_t)row * 32 + fq];
      }
      s.x *= invk; s.y *= invk; s.z *= invk; s.w *= invk;
      sagg4[r][fq] = s;
      sx4[r][fq] = xv;
    }
  }
  __syncthreads();
  int q = t & 31, rg = t >> 5;
  const float4* Wrel4  = (const float4*)Wrel;
  const float4* Wroot4 = (const float4*)Wroot;
  float4 bq = ((const float4*)brel)[q];
  float4 acc[4];
#pragma unroll
  for (int rr = 0; rr < 4; ++rr) acc[rr] = bq;
  int rbase = rg * 4;
#pragma unroll 2
  for (int cq = 0; cq < HID / 4; ++cq) {
    float4 w1[4], w2[4];
#pragma unroll
    for (int uu = 0; uu < 4; ++uu) {
      w1[uu] = Wrel4[(cq * 4 + uu) * 32 + q];
      w2[uu] = Wroot4[(cq * 4 + uu) * 32 + q];
    }
#pragma unroll
    for (int rr = 0; rr < 4; ++rr) {
      float4 a  = sagg4[rbase + rr][cq];
      float4 xx = sx4[rbase + rr][cq];
      acc[rr].x += a.x*w1[0].x + a.y*w1[1].x + a.z*w1[2].x + a.w*w1[3].x
                 + xx.x*w2[0].x + xx.y*w2[1].x + xx.z*w2[2].x + xx.w*w2[3].x;
      acc[rr].y += a.x*w1[0].y + a.y*w1[1].y + a.z*w1[2].y + a.w*w1[3].y
                 + xx.x*w2[0].y + xx.y*w2[1].y + xx.z*w2[2].y + xx.w*w2[3].y;
      acc[rr].z += a.x*w1[0].z + a.y*w1[1].z + a.z*w1[2].z + a.w*w1[3].z
                 + xx.x*w2[0].z + xx.y*w2[1].z + xx.z*w2[2].z + xx.w*w2[3].z;
      acc[rr].w += a.x*w1[0].w + a.y*w1[1].w + a.z*w1[2].w + a.w*w1[3].w
                 + xx.x*w2[0].w + xx.y*w2[1].w + xx.z*w2[2].w + xx.w*w2[3].w;
    }
  }
  float4 wplq = ((const float4*)wprel)[q];
  float4 wprq = ((const float4*)wproot)[q];
#pragma unroll
  for (int rr = 0; rr < 4; ++rr) {
    int row = i0 + rbase + rr;
    float4 v = acc[rr];
    v.x = v.x > 0.f ? v.x : 0.f;
    v.y = v.y > 0.f ? v.y : 0.f;
    v.z = v.z > 0.f ? v.z : 0.f;
    v.w = v.w > 0.f ? v.w : 0.f;
    float pu = 0.f, pv = 0.f;
    if (row < n) {
      ((float4*)out)[(size_t)row * 32 + q] = v;
      pu = v.x * wplq.x + v.y * wplq.y + v.z * wplq.z + v.w * wplq.w;
      pv = v.x * wprq.x + v.y * wprq.y + v.z * wprq.z + v.w * wprq.w;
    }
#pragma unroll
    for (int o = 16; o; o >>= 1) {
      pu += __shfl_down(pu, o, 32);
      pv += __shfl_down(pv, o, 32);
    }
    if (q == 0 && row < n) { uo[row] = pu; vo[row] = pv; }
  }
}

// ---------- scalar score + fused per-block 1024-bin histogram ----------
template <int K>
__global__ __launch_bounds__(256) void k_score_lite(
    const float* __restrict__ u, const float* __restrict__ v,
    const int* __restrict__ src, const float* __restrict__ bprel,
    int n, float* __restrict__ score, unsigned* __restrict__ key,
    unsigned* __restrict__ ghist) {
  __shared__ unsigned lh[1024];
  int t = threadIdx.x;
#pragma unroll
  for (int uu = 0; uu < 4; ++uu) lh[t + uu * 256] = 0u;
  __syncthreads();
  int i = blockIdx.x * 256 + t;
  if (i < n) {
    float s = v[i] + bprel[0];
#pragma unroll
    for (int j = 0; j < K; ++j) s += u[src[i * K + j]];
    float sc = tanhf(s);
    score[i] = sc;
    unsigned bb = __float_as_uint(sc);
    unsigned k2 = (bb & 0x80000000u) ? ~bb : (bb | 0x80000000u);
    key[i] = k2;
    atomicAdd(&lh[k2 >> 22], 1u);
  }
  __syncthreads();
#pragma unroll
  for (int uu = 0; uu < 4; ++uu) {
    unsigned vv = lh[t + uu * 256];
    if (vv) atomicAdd(&ghist[t + uu * 256], vv);
  }
}

// ---------- collect: inline boundary-bin pick + u64 candidate append ----------
__global__ __launch_bounds__(256) void k_collect(
    const unsigned* __restrict__ key, int n, int kk,
    const unsigned* __restrict__ ghist,
    unsigned* __restrict__ BA, unsigned long long* __restrict__ candbuf,
    int* __restrict__ candCnt) {
  __shared__ int wt[4];
  __shared__ unsigned shB, shAbove;
  int t = threadIdx.x;             // 256
  int lane = t & 63, wid = t >> 6;
  unsigned h[4]; int s = 0;
#pragma unroll
  for (int uu = 0; uu < 4; ++uu) { h[uu] = ghist[t * 4 + uu]; s += (int)h[uu]; }
  int is = wave_iscan(s, lane);
  if (lane == 63) wt[wid] = is;
  __syncthreads();
  int b = 0, tot = 0;
#pragma unroll
  for (int w2 = 0; w2 < 4; ++w2) { int ss = wt[w2]; if (w2 < wid) b += ss; tot += ss; }
  int c = b + is - s;
#pragma unroll
  for (int uu = 0; uu < 4; ++uu) {
    c += (int)h[uu];
    unsigned above_strict = (unsigned)(tot - c);
    unsigned above_incl = above_strict + h[uu];
    if (above_incl >= (unsigned)kk && above_strict < (unsigned)kk) {
      shB = (unsigned)(t * 4 + uu);
      shAbove = above_strict;
    }
  }
  __syncthreads();
  unsigned B = shB;
  if (blockIdx.x == 0 && t == 0) { BA[0] = B; BA[1] = shAbove; }
  int i = blockIdx.x * 256 + t;
  unsigned long long lmask = (1ull << lane) - 1ull;
  unsigned kv = (i < n) ? key[i] : 0u;
  bool m = (i < n) && ((kv >> 22) == B);
  unsigned long long mm = __ballot(m);
  if (mm) {
    int leader = (int)(__ffsll((long long)mm) - 1);
    int base = 0;
    if (lane == leader) base = atomicAdd(candCnt, (int)__popcll(mm));
    base = __shfl(base, leader, 64);
    if (m) {
      int p = base + (int)__popcll(mm & lmask);
      if (p < CAND_CAP) candbuf[p] = ((unsigned long long)kv << 32) | (unsigned)(~i);
    }
  }
}

// ---------- refine 54 remaining bits of unique key64 -> exact T64 ----------
// prefix starts at B<<54 (the 10 fixed bin bits) so pass bins are mantissa/idx
// bits (uniform) -> no same-address LDS atomic storms.
__global__ __launch_bounds__(1024) void k_refine(
    const unsigned long long* __restrict__ candbuf, const int* __restrict__ candCnt,
    const unsigned* __restrict__ BA, int kk, unsigned long long* __restrict__ T64) {
  extern __shared__ unsigned long long cands[];   // CAND_CAP u64 = 64 KB
  __shared__ unsigned hist256[256];
  __shared__ unsigned long long sh_prefix;
  __shared__ unsigned sh_remain;
  __shared__ int wtB[4];
  int t = threadIdx.x;
  int lane = t & 63, wid = t >> 6;
  unsigned B = BA[0], above = BA[1];
  int cnt = *candCnt; if (cnt > CAND_CAP) cnt = CAND_CAP;
  for (int i = t; i < cnt; i += 1024) cands[i] = candbuf[i];
  if (t == 0) {
    sh_prefix = ((unsigned long long)B) << 54;
    sh_remain = (unsigned)(kk - (int)above);
  }
  __syncthreads();
  const int shifts[7] = {46, 38, 30, 22, 14, 6, 0};
  for (int p = 0; p < 7; ++p) {
    int shift = shifts[p];
    int bits = (p == 6) ? 6 : 8;
    unsigned mask = (1u << bits) - 1u;
    unsigned long long himask = (p == 0) ? (~0ull << 54)
                                         : (~0ull << (shifts[p - 1]));
    unsigned long long prefix = sh_prefix;
    unsigned rem = sh_remain;
    if (t < 256) hist256[t] = 0u;
    __syncthreads();
    for (int i = t; i < cnt; i += 1024) {
      unsigned long long cc = cands[i];
      if ((cc & himask) == prefix)
        atomicAdd(&hist256[(unsigned)((cc >> shift) & mask)], 1u);
    }
    __syncthreads();
    int hv = (t < 256) ? (int)hist256[t] : 0;
    int iv = wave_iscan(hv, lane);
    if (t < 256 && lane == 63) wtB[wid] = iv;
    __syncthreads();
    if (t < 256) {
      int b = 0, tot = 0;
#pragma unroll
      for (int w2 = 0; w2 < 4; ++w2) { int s = wtB[w2]; if (w2 < wid) b += s; tot += s; }
      unsigned val = (unsigned)(iv + b);
      unsigned sstrict = (unsigned)tot - val;
      if ((unsigned)t <= mask && sstrict < rem && sstrict + (unsigned)hv >= rem) {
        sh_prefix = prefix | ((unsigned long long)t << shift);
        sh_remain = rem - sstrict;
      }
    }
    __syncthreads();
  }
  if (t == 0) T64[0] = sh_prefix;     // unique k-th largest key64
}

// ---------- compaction: keep key64 >= T64 (exactly kk, unordered) ----------
__global__ void k_sel(const unsigned* __restrict__ key, int n,
                      const unsigned long long* __restrict__ T64,
                      int* __restrict__ perm, int* __restrict__ cntSel) {
  int i = blockIdx.x * blockDim.x + threadIdx.x;
  int lane = threadIdx.x & 63;
  unsigned long long lmask = (1ull << lane) - 1ull;
  unsigned long long T = T64[0];
  bool g = false;
  if (i < n) {
    unsigned long long k64 = ((unsigned long long)key[i] << 32) | (unsigned)(~i);
    g = (k64 >= T);
  }
  unsigned long long mg = __ballot(g);
  if (mg) {
    int leader = (int)(__ffsll((long long)mg) - 1);
    int base = 0;
    if (lane == leader) base = atomicAdd(cntSel, (int)__popcll(mg));
    base = __shfl(base, leader, 64);
    if (g) perm[base + (int)__popcll(mg & lmask)] = i;
  }
}

// ---------- pooled gather + per-block column-max + fused grid-cell count ----------
template <int R>
__global__ __launch_bounds__(256) void k_pool_pmax(
    const float* __restrict__ x, const float* __restrict__ score,
    const int* __restrict__ perm, const float* __restrict__ pos_in,
    float* __restrict__ xout, float* __restrict__ pos_out, int store,
    float* __restrict__ pmax, int* __restrict__ counts, int Gg, float inv_w) {
  __shared__ float sm[2][HID];
  int f = threadIdx.x & 127;
  int half = threadIdx.x >> 7;
  int j0 = blockIdx.x * R;
  float mx = -1e30f;
  for (int r = half; r < R; r += 2) {
    int j = j0 + r;
    int node = perm[j];
    float v = score[node];
    float val = x[(size_t)node * HID + f] * v;
    if (store) {
      xout[(size_t)j * HID + f] = val;
      if (f == 0) {
        float px = pos_in[node * 2], py = pos_in[node * 2 + 1];
        pos_out[j * 2] = px; pos_out[j * 2 + 1] = py;
        int cx = min(Gg - 1, max(0, (int)(px * inv_w)));
        int cy = min(Gg - 1, max(0, (int)(py * inv_w)));
        atomicAdd(&counts[cy * Gg + cx], 1);
      }
    }
    mx = fmaxf(mx, val);
  }
  sm[half][f] = mx;
  __syncthreads();
  if (half == 0) pmax[blockIdx.x * HID + f] = fmaxf(sm[0][f], sm[1][f]);
}

// ---------- grid scan (1 block over <=4096 cells) ----------
__global__ __launch_bounds__(1024) void k_grid_scan(const int* __restrict__ counts,
                                                    int* __restrict__ starts,
                                                    int* __restrict__ cursor, int cells) {
  __shared__ int wtA[16];
  int t = threadIdx.x;
  int lane = t & 63, wid = t >> 6;
  int c0[4]; int base4 = t * 4; int s = 0;
#pragma unroll
  for (int u = 0; u < 4; ++u) {
    int idx = base4 + u;
    c0[u] = (idx < cells) ? counts[idx] : 0;
    s += c0[u];
  }
  int is = wave_iscan(s, lane);
  if (lane == 63) wtA[wid] = is;
  __syncthreads();
  int b = 0;
#pragma unroll
  for (int w2 = 0; w2 < 16; ++w2) { if (w2 < wid) b += wtA[w2]; }
  int excl = b + is - s;
#pragma unroll
  for (int u = 0; u < 4; ++u) {
    int idx = base4 + u;
    if (idx < cells) { starts[idx] = excl; cursor[idx] = excl; excl += c0[u]; }
  }
}

__global__ void k_grid_scatter(const float2* __restrict__ pos, int m, int Gg, float inv_w,
                               int* __restrict__ cursor, float2* __restrict__ spos,
                               int* __restrict__ sidx) {
  int i = blockIdx.x * blockDim.x + threadIdx.x;
  if (i >= m) return;
  float2 p = pos[i];
  int cx = min(Gg - 1, max(0, (int)(p.x * inv_w)));
  int cy = min(Gg - 1, max(0, (int)(p.y * inv_w)));
  int pp = atomicAdd(&cursor[cy * Gg + cx], 1);
  spos[pp] = p;
  sidx[pp] = i;
}

// ---------- exact KNN, one wave per query ----------
template <int K>
__global__ __launch_bounds__(256) void k_knn_wave(const float2* __restrict__ spos,
                           const int* __restrict__ sidx,
                           const int* __restrict__ starts, const int* __restrict__ counts,
                           int m, int G, float w, float inv_w, int* __restrict__ src_out) {
  int lane = threadIdx.x & 63;
  int j = blockIdx.x * (blockDim.x >> 6) + (threadIdx.x >> 6);
  if (j >= m) return;
  float2 qp = spos[j];
  int q = sidx[j];
  int cx = min(G - 1, max(0, (int)(qp.x * inv_w)));
  int cy = min(G - 1, max(0, (int)(qp.y * inv_w)));

  float bd[K]; int bi[K];
#pragma unroll
  for (int t = 0; t < K; ++t) { bd[t] = 1e30f; bi[t] = 0; }

  auto scan_span = [&](int s, int e) {
    for (int p = s + lane; p < e; p += 64) {
      if (p == j) continue;
      float2 pp = spos[p];
      float dx = qp.x - pp.x, dy = qp.y - pp.y;
      float d = dx * dx + dy * dy;
      if (d < bd[K - 1]) {
        float dd = d; int ii = sidx[p];
#pragma unroll
        for (int t = 0; t < K; ++t) {
          bool sw = dd < bd[t];
          float od = bd[t]; int oi = bi[t];
          if (sw) { bd[t] = dd; bi[t] = ii; dd = od; ii = oi; }
        }
      }
    }
  };

  {
    int xl = max(0, cx - 1), xh = min(G - 1, cx + 1);
    int y0 = max(0, cy - 1), y1 = min(G - 1, cy + 1);
    int ss[3], ee[3]; int nr = 0;
    for (int y = y0; y <= y1; ++y) {
      int b = y * G;
      ss[nr] = starts[b + xl];
      ee[nr] = starts[b + xh] + counts[b + xh];
      ++nr;
    }
    for (int t = 0; t < nr; ++t) scan_span(ss[t], ee[t]);
  }

  int r = 1;
  unsigned long long mg[K];
  while (true) {
    unsigned long long tmp[K];
#pragma unroll
    for (int t = 0; t < K; ++t)
      tmp[t] = ((unsigned long long)__float_as_uint(bd[t]) << 32) | (unsigned)bi[t];
#pragma unroll
    for (int t = 0; t < K; ++t) {
      unsigned long long mn = tmp[0];
#pragma unroll
      for (int o = 1; o < 64; o <<= 1) {
        unsigned long long ot = __shfl_xor(mn, o, 64);
        if (ot < mn) mn = ot;
      }
      mg[t] = mn;
      if (tmp[0] == mn) {
#pragma unroll
        for (int s2 = 0; s2 < K - 1; ++s2) tmp[s2] = tmp[s2 + 1];
        tmp[K - 1] = ~0ull;
      }
    }
    float kth = __uint_as_float((unsigned)(mg[K - 1] >> 32));
    float bnd = 1e30f;
    if (cx - r > 0)     bnd = fminf(bnd, qp.x - (float)(cx - r) * w);
    if (cx + r < G - 1) bnd = fminf(bnd, (float)(cx + r + 1) * w - qp.x);
    if (cy - r > 0)     bnd = fminf(bnd, qp.y - (float)(cy - r) * w);
    if (cy + r < G - 1) bnd = fminf(bnd, (float)(cy + r + 1) * w - qp.y);
    if (bnd > 1e29f) break;
    float bb = fmaxf(bnd, 0.f) * 0.999f;
    if (kth < bb * bb) break;
    ++r;
    int xl = max(0, cx - r), xh = min(G - 1, cx + r);
    int yt = cy - r, yb = cy + r;
    if (yt >= 0)     { int b = yt * G; scan_span(starts[b + xl], starts[b + xh] + counts[b + xh]); }
    if (yb <= G - 1) { int b = yb * G; scan_span(starts[b + xl], starts[b + xh] + counts[b + xh]); }
    int ylo = max(0, cy - r + 1), yhi = min(G - 1, cy + r - 1);
    for (int y = ylo; y <= yhi; ++y) {
      int b = y * G;
      if (cx - r >= 0)     { int c = b + cx - r; scan_span(starts[c], starts[c] + counts[c]); }
      if (cx + r <= G - 1) { int c = b + cx + r; scan_span(starts[c], starts[c] + counts[c]); }
    }
  }
  if (lane == 0) {
#pragma unroll
    for (int t = 0; t < K; ++t) src_out[q * K + t] = (int)(unsigned)(mg[t] & 0xffffffffu);
  }
}

// ---------- grid-parallel pmax reduction: 24 blocks -> pmax2[3][8][HID] ----------
__global__ __launch_bounds__(256) void k_colmax2(const float* __restrict__ pmax,
                                                 int P0, int P1, int P2,
                                                 float* __restrict__ pmax2) {
  __shared__ float sm[2][HID];
  int l = blockIdx.x >> 3, c = blockIdx.x & 7;
  int lo3[3] = {0, P0, P0 + P1};
  int len3[3] = {P0, P1, P2};
  int lo = lo3[l], len = len3[l];
  int f = threadIdx.x & 127, half = threadIdx.x >> 7;
  float mx = -1e30f;
  for (int p = c + 8 * half; p < len; p += 16)
    mx = fmaxf(mx, pmax[(size_t)(lo + p) * HID + f]);
  sm[half][f] = mx;
  __syncthreads();
  if (half == 0) pmax2[(size_t)blockIdx.x * HID + f] = fmaxf(sm[0][f], sm[1][f]);
}

// ---------- final: tiny reduce (24 rows) + MLP head ----------
__global__ __launch_bounds__(1024) void k_final(const float* __restrict__ pmax2,
                        const float* __restrict__ W1, const float* __restrict__ b1,
                        const float* __restrict__ W2, const float* __restrict__ b2,
                        float* __restrict__ out) {
  __shared__ float sxs[3 * HID];
  __shared__ float red[8][HID];
  __shared__ float h1[HID];
  int f = threadIdx.x & 127, ch = threadIdx.x >> 7;
  if (ch < 3) {
    float mx = pmax2[(size_t)(ch * 8) * HID + f];
#pragma unroll
    for (int u = 1; u < 8; ++u) mx = fmaxf(mx, pmax2[(size_t)(ch * 8 + u) * HID + f]);
    sxs[ch * HID + f] = mx;
  }
  __syncthreads();
  float acc = 0.f;
  for (int c = ch * 48; c < (ch + 1) * 48; ++c) acc += sxs[c] * W1[c * HID + f];
  red[ch][f] = acc;
  __syncthreads();
  if (ch == 0) {
    float a = b1[f];
#pragma unroll
    for (int u = 0; u < 8; ++u) a += red[u][f];
    h1[f] = a > 0.f ? a : 0.f;
  }
  __syncthreads();
  if (threadIdx.x < 5) {
    float a = b2[threadIdx.x];
    for (int c = 0; c < HID; ++c) a += h1[c] * W2[c * 5 + threadIdx.x];
    out[threadIdx.x] = a;
  }
}

extern "C" void kernel_launch(void* const* d_in, const int* in_sizes, int n_in,
                              void* d_out, int out_size, void* d_ws, size_t ws_size,
                              hipStream_t stream) {
  const float* x_in   = (const float*)d_in[0];
  const float* pos_in = (const float*)d_in[1];
  const int*   ei     = (const int*)d_in[2];
  const float* Wrel   = (const float*)d_in[3];
  const float* brel   = (const float*)d_in[4];
  const float* Wroot  = (const float*)d_in[5];
  const float* Wprel  = (const float*)d_in[6];
  const float* bprel  = (const float*)d_in[7];
  const float* Wproot = (const float*)d_in[8];
  const float* W1     = (const float*)d_in[9];
  const float* b1     = (const float*)d_in[10];
  const float* W2     = (const float*)d_in[11];
  const float* b2     = (const float*)d_in[12];
  float* out = (float*)d_out;

  const int N0 = in_sizes[0] / HID;   // 20000
  const int P0 = (N0 / 2) / PR, P1 = (N0 / 4) / PR, P2 = (N0 / 8) / PR;

  char* w = (char*)d_ws;
  float*    xB     = (float*)w;    w += (size_t)N0 * HID * 4;
  float*    xA     = (float*)w;    w += (size_t)(N0 / 2) * HID * 4;
  float*    score  = (float*)w;    w += (size_t)N0 * 4;
  unsigned* key    = (unsigned*)w; w += (size_t)N0 * 4;
  float*    ubuf   = (float*)w;    w += (size_t)N0 * 4;
  float*    vbuf   = (float*)w;    w += (size_t)N0 * 4;
  float*    posA   = (float*)w;    w += (size_t)(N0 / 2) * 2 * 4;
  float*    posB   = (float*)w;    w += (size_t)(N0 / 2) * 2 * 4;
  int*      srcbuf = (int*)w;      w += (size_t)(N0 / 2) * 8 * 4;
  int*      permb  = (int*)w;      w += (size_t)(N0 / 2) * 4;
  float*    pmax   = (float*)w;    w += (size_t)(P0 + P1 + P2) * HID * 4;
  float*    pmax2  = (float*)w;    w += (size_t)24 * HID * 4;
  // single zeroed region: [ghist 3x4KB][cnt 16 ints][counts 2x16KB]
  unsigned* ghistB = (unsigned*)w; w += 3 * 1024 * 4;
  int*      cnt    = (int*)w;      w += 16 * 4;          // candCnt[3], selCnt[3]
  int*      countsB= (int*)w;      w += 2 * MAXCELLS * 4;
  const size_t ZERO_BYTES = 3 * 1024 * 4 + 16 * 4 + 2 * MAXCELLS * 4;
  unsigned long long* T64 = (unsigned long long*)w; w += 16;
  unsigned* BA     = (unsigned*)w; w += 16;
  unsigned long long* candbuf = (unsigned long long*)w; w += CAND_CAP * 8;
  int*      starts = (int*)w;      w += MAXCELLS * 4;
  int*      cursor = (int*)w;      w += MAXCELLS * 4;
  float2*   spos   = (float2*)w;   w += (size_t)(N0 / 2) * 8;
  int*      sidx   = (int*)w;      w += (size_t)(N0 / 2) * 4;
  (void)ws_size; (void)n_in; (void)out_size;

  hipMemsetAsync(ghistB, 0, ZERO_BYTES, stream);   // one upfront zeroing (captured)

  int n = N0;
  const float* xcur   = x_in;
  const float* poscur = pos_in;
  const int*   srccur = ei;
  int kcur = 6;
  int Poff = 0;

  for (int l = 0; l < 3; ++l) {
    const int kk = n / 2;
    int Gg = (int)ceilf(sqrtf((float)kk / 2.5f));
    if (Gg > 64) Gg = 64;
    if (Gg < 1) Gg = 1;
    int cells = Gg * Gg;
    float cw = 100.f / (float)Gg;
    float inv_w = (float)Gg / 100.f;
    int cblocks = (n + CRPB - 1) / CRPB;
    unsigned* ghist = ghistB + l * 1024;
    int* counts = countsB + (l < 2 ? l : 0) * MAXCELLS;

    if (kcur == 6) {
      k_conv_fused<6><<<cblocks, 256, 0, stream>>>(xcur, srccur, n, 1.f / 6.f,
          Wrel + l * HID * HID, Wroot + l * HID * HID, brel + l * HID,
          Wprel + l * HID, Wproot + l * HID, xB, ubuf, vbuf);
      k_score_lite<6><<<(n + 255) / 256, 256, 0, stream>>>(ubuf, vbuf, srccur, bprel + l,
                                                           n, score, key, ghist);
    } else {
      k_conv_fused<8><<<cblocks, 256, 0, stream>>>(xcur, srccur, n, 1.f / 8.f,
          Wrel + l * HID * HID, Wroot + l * HID * HID, brel + l * HID,
          Wprel + l * HID, Wproot + l * HID, xB, ubuf, vbuf);
      k_score_lite<8><<<(n + 255) / 256, 256, 0, stream>>>(ubuf, vbuf, srccur, bprel + l,
                                                           n, score, key, ghist);
    }
    k_collect<<<(n + 255) / 256, 256, 0, stream>>>(key, n, kk, ghist, BA, candbuf, cnt + 2 * l);
    k_refine<<<1, 1024, CAND_CAP * 8, stream>>>(candbuf, cnt + 2 * l, BA, kk, T64);
    k_sel<<<(n + 255) / 256, 256, 0, stream>>>(key, n, T64, permb, cnt + 2 * l + 1);

    float* pos_out = (l == 0) ? posA : posB;
    int store = (l < 2) ? 1 : 0;
    k_pool_pmax<PR><<<kk / PR, 256, 0, stream>>>(xB, score, permb, poscur, xA, pos_out,
                                                 store, pmax + (size_t)Poff * HID,
                                                 counts, Gg, inv_w);
    Poff += kk / PR;
    n = kk;
    if (l < 2) {
      k_grid_scan<<<1, 1024, 0, stream>>>(counts, starts, cursor, cells);
      k_grid_scatter<<<(n + 255) / 256, 256, 0, stream>>>((const float2*)pos_out, n, Gg, inv_w,
                                                          cursor, spos, sidx);
      if (l == 0) { k_knn_wave<6><<<(n + 3) / 4, 256, 0, stream>>>(spos, sidx, starts, counts,
                                                                   n, Gg, cw, inv_w, srcbuf); kcur = 6; }
      else        { k_knn_wave<8><<<(n + 3) / 4, 256, 0, stream>>>(spos, sidx, starts, counts,
                                                                   n, Gg, cw, inv_w, srcbuf); kcur = 8; }
    }
    xcur = xA; poscur = pos_out; srccur = srcbuf;
  }
  k_colmax2<<<24, 256, 0, stream>>>(pmax, P0, P1, P2, pmax2);
  k_final<<<1, 1024, 0, stream>>>(pmax2, W1, b1, W2, b2, out);
}